// Round 5
// baseline (295.450 us; speedup 1.0000x reference)
//
#include <hip/hip_runtime.h>

typedef short bf16x8 __attribute__((ext_vector_type(8)));
typedef float f32x4 __attribute__((ext_vector_type(4)));

#define ELLK 32
#define OCAP 4096
#define CSTRIDE 16  // ints between degree counters (64B apart): no same-line atomic aliasing

static __device__ __forceinline__ float4 f4zero() { return make_float4(0.f, 0.f, 0.f, 0.f); }

// round-to-nearest-even f32 -> bf16
static __device__ __forceinline__ unsigned short f2bf(float f) {
  unsigned u = __float_as_uint(f);
  u += 0x7FFFu + ((u >> 16) & 1u);
  return (unsigned short)(u >> 16);
}
// packed pair of bf16 (low = first elem) -> float2
static __device__ __forceinline__ float2 bf2x2(unsigned u) {
  float2 r;
  r.x = __uint_as_float(u << 16);
  r.y = __uint_as_float(u & 0xFFFF0000u);
  return r;
}

// ---------- setup: zero counters/ocount/pad-rows + weights -> bf16 in MFMA-FRAGMENT order ----------
// Wt[frag] layout: frag id = ((kk*8+nt)*64 + lane)*8 + j, element = W[k= kk*32+quad*8+j][nn= nt*16+li]
// -> a wave's B-fragment load for (kk,nt) is 16B/lane fully coalesced from the L2-hot 32KB table.
__global__ void k_setup(const float* __restrict__ W1, const float* __restrict__ Wmu,
                        const float* __restrict__ Wlv, unsigned short* __restrict__ Wt1,
                        unsigned short* __restrict__ Wt2, uint4* __restrict__ cntz,
                        int* __restrict__ ocount, unsigned* __restrict__ A,
                        unsigned* __restrict__ H, int nz4, int nbz, int n) {
  int b = blockIdx.x;
  if (b < nbz) {
    int i = b * 256 + threadIdx.x;
    if (i < nz4) cntz[i] = make_uint4(0u, 0u, 0u, 0u);
    if (b == 0) {
      int t = threadIdx.x;
      if (t == 0) *ocount = 0;
      if (t < 64) A[(size_t)n * 64 + t] = 0u;               // zero pad row (A)
      else if (t < 128) H[(size_t)n * 64 + (t - 64)] = 0u;  // zero pad row (H)
    }
  } else {
    int id = (b - nbz) * 256 + threadIdx.x;  // 0..32767
    if (id < 16384) {
      int j = id & 7, lane = (id >> 3) & 63, g = id >> 9;  // g = kk*8+nt
      int kk = g >> 3, nt = g & 7, li = lane & 15, quad = lane >> 4;
      int nn = nt * 16 + li, k = kk * 32 + quad * 8 + j;
      Wt1[id] = f2bf(W1[k * 128 + nn]);
    } else {
      int id2 = id - 16384;
      int j = id2 & 7, lane = (id2 >> 3) & 63, g = id2 >> 9;
      int kk = g >> 3, nt = g & 7, li = lane & 15, quad = lane >> 4;
      int nn = nt * 16 + li, k = kk * 32 + quad * 8 + j;
      float v = (nn < 64) ? Wmu[k * 64 + nn] : Wlv[k * 64 + (nn - 64)];
      Wt2[id2] = f2bf(v);
    }
  }
}

// ---------- FUSED: ELL fill (latency-bound, blocks [0,eb)) + GEMM1 (streaming, rest) ----------
// gemm1 writes RAW A = bf16(x @ W1) -- no cnt dependency, so fill and gemm co-reside.
// LDS = Xl only (17.4KB) so fill blocks keep 4 blocks/CU (16 waves) occupancy.
__global__ __launch_bounds__(256, 4) void k_fill_gemm1(
    const float* __restrict__ x, const unsigned short* __restrict__ Wt,
    const int* __restrict__ ei, int* __restrict__ cnt, int* __restrict__ ell,
    int2* __restrict__ ovf, int* __restrict__ ocount,
    unsigned short* __restrict__ A, int E, int n, int eb) {
  __shared__ unsigned short Xl[64 * 136];
  const int tid = threadIdx.x;

  if (blockIdx.x < eb) {  // ---- fill path: 4 edges/thread, transposed ELL planes ----
    int e0 = blockIdx.x * 1024 + tid;
    int ss[4], dd[4], pos[4];
    bool ok[4];
#pragma unroll
    for (int k = 0; k < 4; ++k) {
      int e = e0 + k * 256;
      ok[k] = (e < E);
      ss[k] = ok[k] ? ei[e] : 0;
      dd[k] = ok[k] ? ei[E + e] : 0;
    }
#pragma unroll
    for (int k = 0; k < 4; ++k)
      pos[k] = ok[k] ? atomicAdd(&cnt[(size_t)dd[k] * CSTRIDE], 1) : ELLK;
#pragma unroll
    for (int k = 0; k < 4; ++k) {
      if (!ok[k]) continue;
      if (pos[k] < ELLK) {
        __builtin_nontemporal_store(ss[k], &ell[(size_t)pos[k] * n + dd[k]]);
      } else {
        int o = atomicAdd(ocount, 1);
        if (o < OCAP) ovf[o] = make_int2(dd[k], ss[k]);
      }
    }
    return;
  }

  // ---- gemm1 path ----
  const int row0 = (blockIdx.x - eb) * 64;
  {
#pragma unroll
    for (int i = 0; i < 8; ++i) {
      int idx = tid + i * 256;  // 0..2047
      int r = idx >> 5, c = idx & 31;
      int gi = row0 + r;
      float4 v = (gi < n) ? ((const float4*)x)[(size_t)gi * 32 + c] : f4zero();
      ushort4 p;
      p.x = f2bf(v.x); p.y = f2bf(v.y); p.z = f2bf(v.z); p.w = f2bf(v.w);
      *(ushort4*)&Xl[r * 136 + c * 4] = p;
    }
  }
  __syncthreads();

  const int wave = tid >> 6, lane = tid & 63;
  const int li = lane & 15, quad = lane >> 4;
  const int m0 = wave * 16;
  const bf16x8* Wf = (const bf16x8*)Wt;
  f32x4 acc[8];
#pragma unroll
  for (int t = 0; t < 8; ++t) acc[t] = (f32x4){0.f, 0.f, 0.f, 0.f};

#pragma unroll
  for (int kk = 0; kk < 4; ++kk) {
    int ko = kk * 32 + quad * 8;
    bf16x8 a = *(const bf16x8*)&Xl[(m0 + li) * 136 + ko];
    bf16x8 bf[8];
#pragma unroll
    for (int nt = 0; nt < 8; ++nt) bf[nt] = Wf[(kk * 8 + nt) * 64 + lane];
#pragma unroll
    for (int nt = 0; nt < 8; ++nt)
      acc[nt] = __builtin_amdgcn_mfma_f32_16x16x32_bf16(a, bf[nt], acc[nt], 0, 0, 0);
  }
  __syncthreads();  // MFMA reads of Xl done
#pragma unroll
  for (int nt = 0; nt < 8; ++nt)
#pragma unroll
    for (int r = 0; r < 4; ++r)
      Xl[(m0 + quad * 4 + r) * 136 + nt * 16 + li] = f2bf(acc[nt][r]);
  __syncthreads();
  {
    uint4* A4 = (uint4*)A;
#pragma unroll
    for (int i = 0; i < 4; ++i) {
      int idx = tid + i * 256;  // 0..1023
      int r = idx >> 4, c = idx & 15;
      int gi = row0 + r;
      if (gi < n) A4[(size_t)gi * 16 + c] = *(uint4*)&Xl[r * 136 + c * 8];
    }
  }
}

// ---------- dnorm: densify cnt -> dnorm[i]=rsqrt(deg), mflag = min(c,32)|ovf; dnorm[n]=0 ----------
__global__ void k_dnorm(const int* __restrict__ cnt, float* __restrict__ dnorm,
                        unsigned* __restrict__ mflag, int n) {
  int i = blockIdx.x * 256 + threadIdx.x;
  if (i > n) return;
  if (i == n) { dnorm[n] = 0.f; mflag[n] = 0u; return; }  // pad row
  int c = cnt[(size_t)i * CSTRIDE];
  dnorm[i] = rsqrtf((float)(c + 1));
  int m = (c < ELLK) ? c : ELLK;
  mflag[i] = (unsigned)m | ((c > ELLK) ? 0x80000000u : 0u);
}

// ---------- SpMM over transposed ELL, one wave/node, exact ceil(m/8) batches ----------
// L1: acc = dis_i*A_i + sum_j dnorm[src_j]*A_j ; H_bar = dis_i*relu(dis_i*acc + b)  (pre-scaled)
// L2: pure row-sum of pre-scaled H_bar; G = dis_i*acc
template <bool L1>
__global__ __launch_bounds__(256) void k_spmm(
    const unsigned* __restrict__ mflag, const float* __restrict__ dnorm,
    const int* __restrict__ ell, const int2* __restrict__ ovf,
    const int* __restrict__ ocount, const unsigned* __restrict__ S,
    unsigned* __restrict__ D, const float2* __restrict__ bias, int n) {
  int wid = (blockIdx.x * blockDim.x + threadIdx.x) >> 6;
  if (wid >= n) return;
  int lane = threadIdx.x & 63;

  unsigned mf = mflag[wid];
  int m = (int)(mf & 0xFFFFu);
  float dsd = dnorm[wid];
  float2 acc = bf2x2(S[(size_t)wid * 64 + lane]);  // own row
  if (L1) { acc.x *= dsd; acc.y *= dsd; }          // self term dis_i * A_i

  const int* ep = ell + wid;  // plane stride = n
  int nbt = (m + 7) >> 3;
  for (int b = 0; b < nbt; ++b) {
    int j0 = b * 8;
    int idx[8];
#pragma unroll
    for (int k = 0; k < 8; ++k) idx[k] = ep[(size_t)(j0 + k) * n];
#pragma unroll
    for (int k = 0; k < 8; ++k) idx[k] = (j0 + k < m) ? idx[k] : n;  // pads -> zero row
    unsigned u[8];
#pragma unroll
    for (int k = 0; k < 8; ++k) u[k] = S[(size_t)idx[k] * 64 + lane];
    float w[8];
    if (L1) {
#pragma unroll
      for (int k = 0; k < 8; ++k) w[k] = dnorm[idx[k]];  // 400KB table, L2-hot; dnorm[n]=0
    }
#pragma unroll
    for (int k = 0; k < 8; ++k) {
      float2 f = bf2x2(u[k]);
      if (L1) { acc.x = fmaf(w[k], f.x, acc.x); acc.y = fmaf(w[k], f.y, acc.y); }
      else    { acc.x += f.x; acc.y += f.y; }
    }
  }
  if (mf & 0x80000000u) {  // pathological high-degree nodes: scan tiny overflow list
    int oc = *ocount;
    if (oc > OCAP) oc = OCAP;
    for (int k = 0; k < oc; ++k) {
      int2 e = ovf[k];
      if (e.x == wid) {
        float2 u0 = bf2x2(S[(size_t)e.y * 64 + lane]);
        float wv = L1 ? dnorm[e.y] : 1.f;
        acc.x = fmaf(wv, u0.x, acc.x); acc.y = fmaf(wv, u0.y, acc.y);
      }
    }
  }
  float2 o;
  if (L1) {
    float2 b = bias[lane];
    o.x = dsd * fmaxf(fmaf(dsd, acc.x, b.x), 0.f);
    o.y = dsd * fmaxf(fmaf(dsd, acc.y, b.y), 0.f);
  } else {
    o.x = dsd * acc.x;
    o.y = dsd * acc.y;
  }
  unsigned pk = (unsigned)f2bf(o.x) | ((unsigned)f2bf(o.y) << 16);
  D[(size_t)wid * 64 + lane] = pk;
}

// ---------- GEMM2 (MFMA, fragment-W, Xl-only LDS): out = [G@Wmu+bmu | G@Wlv+blv] ----------
__global__ __launch_bounds__(256, 4) void k_gemm2_mfma(
    const unsigned short* __restrict__ G, const unsigned short* __restrict__ Wt,
    const float* __restrict__ bmu, const float* __restrict__ blv,
    float* __restrict__ out, int n) {
  __shared__ unsigned short Xl[64 * 136];
  const int tid = threadIdx.x;
  const int row0 = blockIdx.x * 64;
  {
    const uint4* Gg = (const uint4*)G;
#pragma unroll
    for (int i = 0; i < 4; ++i) {
      int idx = tid + i * 256;  // 0..1023
      int r = idx >> 4, c = idx & 15;
      int gi = row0 + r;
      uint4 v = (gi < n) ? Gg[(size_t)gi * 16 + c] : make_uint4(0, 0, 0, 0);
      *(uint4*)&Xl[r * 136 + c * 8] = v;
    }
  }
  __syncthreads();

  const int wave = tid >> 6, lane = tid & 63;
  const int li = lane & 15, quad = lane >> 4;
  const int m0 = wave * 16;
  const bf16x8* Wf = (const bf16x8*)Wt;

  float bias[8];
#pragma unroll
  for (int nt = 0; nt < 8; ++nt) {
    int c = nt * 16 + li;
    bias[nt] = (c < 64) ? bmu[c] : blv[c - 64];
  }

  f32x4 acc[8];
#pragma unroll
  for (int t = 0; t < 8; ++t) acc[t] = (f32x4){0.f, 0.f, 0.f, 0.f};

#pragma unroll
  for (int kk = 0; kk < 4; ++kk) {
    int ko = kk * 32 + quad * 8;
    bf16x8 a = *(const bf16x8*)&Xl[(m0 + li) * 136 + ko];
    bf16x8 bf[8];
#pragma unroll
    for (int nt = 0; nt < 8; ++nt) bf[nt] = Wf[(kk * 8 + nt) * 64 + lane];
#pragma unroll
    for (int nt = 0; nt < 8; ++nt)
      acc[nt] = __builtin_amdgcn_mfma_f32_16x16x32_bf16(a, bf[nt], acc[nt], 0, 0, 0);
  }
#pragma unroll
  for (int nt = 0; nt < 8; ++nt) {
    int col = nt * 16 + li;
#pragma unroll
    for (int r = 0; r < 4; ++r) {
      int gi = row0 + m0 + quad * 4 + r;
      if (gi < n) {
        float v = acc[nt][r] + bias[nt];
        if (col < 64) out[(size_t)gi * 64 + col] = v;              // mu
        else          out[(size_t)(n + gi) * 64 + (col - 64)] = v; // logvar
      }
    }
  }
}

extern "C" void kernel_launch(void* const* d_in, const int* in_sizes, int n_in,
                              void* d_out, int out_size, void* d_ws, size_t ws_size,
                              hipStream_t stream) {
  const float* x   = (const float*)d_in[0];
  const int*   ei  = (const int*)d_in[1];   // [2, E], row0 = src, row1 = dst
  const float* W1  = (const float*)d_in[3];
  const float* b1  = (const float*)d_in[4];
  const float* Wmu = (const float*)d_in[5];
  const float* bmu = (const float*)d_in[6];
  const float* Wlv = (const float*)d_in[7];
  const float* blv = (const float*)d_in[8];
  float* out = (float*)d_out;

  const int n = in_sizes[0] / 128;
  const int E = in_sizes[1] / 2;

  // workspace layout (float units)
  float* ws = (float*)d_ws;
  size_t p = 0;
  int* cnt    = (int*)(ws + p); p += (size_t)n * CSTRIDE;  // spread counters (64B apart)
  int* ocount = (int*)(ws + p); p += 1;
  p = (p + 3) & ~(size_t)3;  // 16B align
  int* ell    = (int*)(ws + p); p += (size_t)n * ELLK;     // TRANSPOSED: [ELLK][n]
  int2* ovf   = (int2*)(ws + p); p += (size_t)OCAP * 2;
  unsigned* A = (unsigned*)(ws + p); p += (size_t)(n + 1) * 64;  // +1: zero pad row
  unsigned* H = (unsigned*)(ws + p); p += (size_t)(n + 1) * 64;
  unsigned* G = (unsigned*)(ws + p); p += (size_t)n * 64;
  unsigned short* Wt1 = (unsigned short*)(ws + p); p += 8192;  // 128x128 bf16 (fragment order)
  unsigned short* Wt2 = (unsigned short*)(ws + p); p += 8192;
  float* dnorm    = (float*)(ws + p); p += n + 1;
  unsigned* mflag = (unsigned*)(ws + p); p += n + 1;

  int nz4  = (n * CSTRIDE) / 4;        // uint4 count for counter zeroing
  int nbz  = (nz4 + 255) / 256;
  int eb   = (E + 1023) / 1024;        // 4 edges per thread
  int gblk = (n + 63) / 64;
  int nb   = (n + 256) / 256;          // covers i == n (pad entry)
  int sblk = (n + 3) / 4;              // one wave per node

  // 1) zero counters/ocount/pad-rows + fragment-ordered weight transpose
  k_setup<<<nbz + 128, 256, 0, stream>>>(W1, Wmu, Wlv, Wt1, Wt2, (uint4*)cnt, ocount,
                                         A, H, nz4, nbz, n);
  // 2) FUSED: ELL build (latency-bound) || A = bf16(x @ W1) raw (streaming)
  k_fill_gemm1<<<eb + gblk, 256, 0, stream>>>(x, Wt1, ei, cnt, ell, ovf, ocount,
                                              (unsigned short*)A, E, n, eb);
  // 3) densify degree norms
  k_dnorm<<<nb, 256, 0, stream>>>(cnt, dnorm, mflag, n);
  // 4) layer 1: H_bar = dis*relu(dis*(dis_i*A_i + sum dnorm[src]*A_src) + b1)
  k_spmm<true><<<sblk, 256, 0, stream>>>(mflag, dnorm, ell, ovf, ocount, A, H,
                                         (const float2*)b1, n);
  // 5) layer 2: G = dis * sum(H_bar)
  k_spmm<false><<<sblk, 256, 0, stream>>>(mflag, dnorm, ell, ovf, ocount, H, G, nullptr, n);
  // 6) out = [G@Wmu+bmu | G@Wlv+blv]
  k_gemm2_mfma<<<gblk, 256, 0, stream>>>((const unsigned short*)G, Wt2, bmu, blv, out, n);
}

// Round 6
// 282.636 us; speedup vs baseline: 1.0453x; 1.0453x over previous
//
#include <hip/hip_runtime.h>

typedef short bf16x8 __attribute__((ext_vector_type(8)));
typedef float f32x4 __attribute__((ext_vector_type(4)));

#define ELLK 32
#define OCAP 4096
#define CSTRIDE 16  // ints between degree counters (64B apart): no same-line atomic aliasing

static __device__ __forceinline__ float4 f4zero() { return make_float4(0.f, 0.f, 0.f, 0.f); }

// round-to-nearest-even f32 -> bf16
static __device__ __forceinline__ unsigned short f2bf(float f) {
  unsigned u = __float_as_uint(f);
  u += 0x7FFFu + ((u >> 16) & 1u);
  return (unsigned short)(u >> 16);
}
// packed pair of bf16 (low = first elem) -> float2
static __device__ __forceinline__ float2 bf2x2(unsigned u) {
  float2 r;
  r.x = __uint_as_float(u << 16);
  r.y = __uint_as_float(u & 0xFFFF0000u);
  return r;
}

// ---------- setup: zero counters/ocount/pad-rows + weights -> bf16 in MFMA-FRAGMENT order ----------
// Wt[frag]: id = ((kk*8+nt)*64 + lane)*8 + j  ->  W[k = kk*32+quad*8+j][nn = nt*16+li]
// so a wave's B-fragment load for (kk,nt) is 16B/lane fully coalesced from the L2-hot 32KB table.
__global__ void k_setup(const float* __restrict__ W1, const float* __restrict__ Wmu,
                        const float* __restrict__ Wlv, unsigned short* __restrict__ Wt1,
                        unsigned short* __restrict__ Wt2, uint4* __restrict__ cntz,
                        int* __restrict__ ocount, unsigned* __restrict__ A,
                        unsigned* __restrict__ H, int nz4, int nbz, int n) {
  int b = blockIdx.x;
  if (b < nbz) {
    int i = b * 256 + threadIdx.x;
    if (i < nz4) cntz[i] = make_uint4(0u, 0u, 0u, 0u);
    if (b == 0) {
      int t = threadIdx.x;
      if (t == 0) *ocount = 0;
      if (t < 64) A[(size_t)n * 64 + t] = 0u;               // zero pad row (A)
      else if (t < 128) H[(size_t)n * 64 + (t - 64)] = 0u;  // zero pad row (H)
    }
  } else {
    int id = (b - nbz) * 256 + threadIdx.x;  // 0..32767
    if (id < 16384) {
      int j = id & 7, lane = (id >> 3) & 63, g = id >> 9;  // g = kk*8+nt
      int kk = g >> 3, nt = g & 7, li = lane & 15, quad = lane >> 4;
      int nn = nt * 16 + li, k = kk * 32 + quad * 8 + j;
      Wt1[id] = f2bf(W1[k * 128 + nn]);
    } else {
      int id2 = id - 16384;
      int j = id2 & 7, lane = (id2 >> 3) & 63, g = id2 >> 9;
      int kk = g >> 3, nt = g & 7, li = lane & 15, quad = lane >> 4;
      int nn = nt * 16 + li, k = kk * 32 + quad * 8 + j;
      float v = (nn < 64) ? Wmu[k * 64 + nn] : Wlv[k * 64 + (nn - 64)];
      Wt2[id2] = f2bf(v);
    }
  }
}

// ---------- ELL fill (TRANSPOSED layout ell[pos][n]): 4 edges/thread ----------
__global__ void k_fill(const int* __restrict__ ei, int* __restrict__ cnt,
                       int* __restrict__ ell, int2* __restrict__ ovf,
                       int* __restrict__ ocount, int E, int n) {
  int e0 = blockIdx.x * 1024 + threadIdx.x;
  int ss[4], dd[4], pos[4];
  bool ok[4];
#pragma unroll
  for (int k = 0; k < 4; ++k) {
    int e = e0 + k * 256;
    ok[k] = (e < E);
    ss[k] = ok[k] ? ei[e] : 0;
    dd[k] = ok[k] ? ei[E + e] : 0;
  }
#pragma unroll
  for (int k = 0; k < 4; ++k)
    pos[k] = ok[k] ? atomicAdd(&cnt[(size_t)dd[k] * CSTRIDE], 1) : ELLK;
#pragma unroll
  for (int k = 0; k < 4; ++k) {
    if (!ok[k]) continue;
    if (pos[k] < ELLK) {
      __builtin_nontemporal_store(ss[k], &ell[(size_t)pos[k] * n + dd[k]]);
    } else {
      int o = atomicAdd(ocount, 1);
      if (o < OCAP) ovf[o] = make_int2(dd[k], ss[k]);
    }
  }
}

// ---------- GEMM1 (MFMA, fragment-W): A = bf16(dis_i * (x @ W1)); emits dnorm/mflag ----------
__global__ __launch_bounds__(256, 4) void k_gemm1(
    const float* __restrict__ x, const unsigned short* __restrict__ Wt,
    const int* __restrict__ cnt, unsigned short* __restrict__ A,
    float* __restrict__ dnorm, unsigned* __restrict__ mflag, int n) {
  __shared__ unsigned short Xl[64 * 136];
  __shared__ float dnl[64];
  const int tid = threadIdx.x;
  const int row0 = blockIdx.x * 64;
  {
#pragma unroll
    for (int i = 0; i < 8; ++i) {
      int idx = tid + i * 256;  // 0..2047
      int r = idx >> 5, c = idx & 31;
      int gi = row0 + r;
      float4 v = (gi < n) ? ((const float4*)x)[(size_t)gi * 32 + c] : f4zero();
      ushort4 p;
      p.x = f2bf(v.x); p.y = f2bf(v.y); p.z = f2bf(v.z); p.w = f2bf(v.w);
      *(ushort4*)&Xl[r * 136 + c * 4] = p;
    }
  }
  // side product: dnorm/mflag for this block's rows (cnt is L2-hot after fill)
  if (tid < 64) {
    int gi = row0 + tid;
    float dn = 0.f;
    if (gi < n) {
      int c = cnt[(size_t)gi * CSTRIDE];
      dn = rsqrtf((float)(c + 1));
      dnorm[gi] = dn;
      int mm = (c < ELLK) ? c : ELLK;
      mflag[gi] = (unsigned)mm | ((c > ELLK) ? 0x80000000u : 0u);
    }
    dnl[tid] = dn;
  }
  __syncthreads();

  const int wave = tid >> 6, lane = tid & 63;
  const int li = lane & 15, quad = lane >> 4;
  const int m0 = wave * 16;
  const bf16x8* Wf = (const bf16x8*)Wt;
  f32x4 acc[8];
#pragma unroll
  for (int t = 0; t < 8; ++t) acc[t] = (f32x4){0.f, 0.f, 0.f, 0.f};

#pragma unroll
  for (int kk = 0; kk < 4; ++kk) {
    int ko = kk * 32 + quad * 8;
    bf16x8 a = *(const bf16x8*)&Xl[(m0 + li) * 136 + ko];
    bf16x8 bf[8];
#pragma unroll
    for (int nt = 0; nt < 8; ++nt) bf[nt] = Wf[(kk * 8 + nt) * 64 + lane];
#pragma unroll
    for (int nt = 0; nt < 8; ++nt)
      acc[nt] = __builtin_amdgcn_mfma_f32_16x16x32_bf16(a, bf[nt], acc[nt], 0, 0, 0);
  }
  __syncthreads();  // MFMA reads of Xl done
  float dn[4];
#pragma unroll
  for (int r = 0; r < 4; ++r) dn[r] = dnl[m0 + quad * 4 + r];
#pragma unroll
  for (int nt = 0; nt < 8; ++nt)
#pragma unroll
    for (int r = 0; r < 4; ++r)
      Xl[(m0 + quad * 4 + r) * 136 + nt * 16 + li] = f2bf(acc[nt][r] * dn[r]);
  __syncthreads();
  {
    uint4* A4 = (uint4*)A;
#pragma unroll
    for (int i = 0; i < 4; ++i) {
      int idx = tid + i * 256;  // 0..1023
      int r = idx >> 4, c = idx & 15;
      int gi = row0 + r;
      if (gi < n) A4[(size_t)gi * 16 + c] = *(uint4*)&Xl[r * 136 + c * 8];
    }
  }
}

// ---------- SpMM layer 1: one wave/node, pure row-sum of pre-scaled A_bar ----------
// acc = dis_i*A_i(pre-scaled rows include src scale); H_bar = dis_i*relu(dis_i_correction...)
// (A rows are dis_src-scaled, self term included; epilogue: dis_i*relu(dis_i*sum... see notes)
__global__ __launch_bounds__(256) void k_spmm1(
    const unsigned* __restrict__ mflag, const float* __restrict__ dnorm,
    const int* __restrict__ ell, const int2* __restrict__ ovf,
    const int* __restrict__ ocount, const unsigned* __restrict__ S,
    unsigned* __restrict__ D, const float2* __restrict__ bias, int n) {
  int wid = (blockIdx.x * blockDim.x + threadIdx.x) >> 6;
  if (wid >= n) return;
  int lane = threadIdx.x & 63;

  unsigned mf = mflag[wid];
  int m = (int)(mf & 0xFFFFu);
  float dsd = dnorm[wid];
  float2 acc = bf2x2(S[(size_t)wid * 64 + lane]);  // own row (self-loop; pre-scaled by dis_i)

  const int* ep = ell + wid;  // plane stride = n
  int nbt = (m + 7) >> 3;
  for (int b = 0; b < nbt; ++b) {
    int j0 = b * 8;
    int idx[8];
#pragma unroll
    for (int k = 0; k < 8; ++k) idx[k] = ep[(size_t)(j0 + k) * n];
#pragma unroll
    for (int k = 0; k < 8; ++k) idx[k] = (j0 + k < m) ? idx[k] : n;  // pads -> zero row
    unsigned u[8];
#pragma unroll
    for (int k = 0; k < 8; ++k) u[k] = S[(size_t)idx[k] * 64 + lane];
#pragma unroll
    for (int k = 0; k < 8; ++k) {
      float2 f = bf2x2(u[k]);
      acc.x += f.x;
      acc.y += f.y;
    }
  }
  if (mf & 0x80000000u) {  // overflow list scan (rare)
    int oc = *ocount;
    if (oc > OCAP) oc = OCAP;
    for (int k = 0; k < oc; ++k) {
      int2 e = ovf[k];
      if (e.x == wid) {
        float2 u0 = bf2x2(S[(size_t)e.y * 64 + lane]);
        acc.x += u0.x;
        acc.y += u0.y;
      }
    }
  }
  float2 b = bias[lane];
  float2 o;
  // out1 = dis_i*acc + b ; store H_bar = dis_i * relu(out1)  (pre-scaled for layer 2)
  o.x = dsd * fmaxf(fmaf(dsd, acc.x, b.x), 0.f);
  o.y = dsd * fmaxf(fmaf(dsd, acc.y, b.y), 0.f);
  unsigned pk = (unsigned)f2bf(o.x) | ((unsigned)f2bf(o.y) << 16);
  D[(size_t)wid * 64 + lane] = pk;
}

// ---------- FUSED SpMM layer 2 + GEMM2: G never hits global memory ----------
// phase 1: each of 4 waves aggregates 16 nodes (8-deep gather batches), G rows -> LDS
// phase 2: MFMA with fragment-W: out = [G@Wmu+bmu | G@Wlv+blv]
__global__ __launch_bounds__(256, 4) void k_spmm2_gemm2(
    const unsigned* __restrict__ mflag, const float* __restrict__ dnorm,
    const int* __restrict__ ell, const int2* __restrict__ ovf,
    const int* __restrict__ ocount, const unsigned* __restrict__ H,
    const unsigned short* __restrict__ Wt, const float* __restrict__ bmu,
    const float* __restrict__ blv, float* __restrict__ out, int n) {
  __shared__ unsigned short Xl[64 * 136];
  const int tid = threadIdx.x;
  const int wave = tid >> 6, lane = tid & 63;
  const int row0 = blockIdx.x * 64;

  // ---- phase 1: aggregate 16 nodes per wave into LDS G-tile ----
#pragma unroll 1
  for (int i = 0; i < 16; ++i) {
    int nd = row0 + wave * 16 + i;
    unsigned pk = 0u;
    if (nd < n) {
      unsigned mf = mflag[nd];
      int m = (int)(mf & 0xFFFFu);
      float dsd = dnorm[nd];
      float2 acc = bf2x2(H[(size_t)nd * 64 + lane]);  // own row (pre-scaled)
      const int* ep = ell + nd;
      int nbt = (m + 7) >> 3;
      for (int b = 0; b < nbt; ++b) {
        int j0 = b * 8;
        int idx[8];
#pragma unroll
        for (int k = 0; k < 8; ++k) idx[k] = ep[(size_t)(j0 + k) * n];
#pragma unroll
        for (int k = 0; k < 8; ++k) idx[k] = (j0 + k < m) ? idx[k] : n;
        unsigned u[8];
#pragma unroll
        for (int k = 0; k < 8; ++k) u[k] = H[(size_t)idx[k] * 64 + lane];
#pragma unroll
        for (int k = 0; k < 8; ++k) {
          float2 f = bf2x2(u[k]);
          acc.x += f.x;
          acc.y += f.y;
        }
      }
      if (mf & 0x80000000u) {
        int oc = *ocount;
        if (oc > OCAP) oc = OCAP;
        for (int k = 0; k < oc; ++k) {
          int2 e = ovf[k];
          if (e.x == nd) {
            float2 u0 = bf2x2(H[(size_t)e.y * 64 + lane]);
            acc.x += u0.x;
            acc.y += u0.y;
          }
        }
      }
      float2 o;
      o.x = dsd * acc.x;
      o.y = dsd * acc.y;
      pk = (unsigned)f2bf(o.x) | ((unsigned)f2bf(o.y) << 16);
    }
    *(unsigned*)&Xl[(wave * 16 + i) * 136 + 2 * lane] = pk;  // G row -> LDS
  }
  __syncthreads();

  // ---- phase 2: MFMA ----
  const int li = lane & 15, quad = lane >> 4;
  const int m0 = wave * 16;
  const bf16x8* Wf = (const bf16x8*)Wt;

  float bias[8];
#pragma unroll
  for (int nt = 0; nt < 8; ++nt) {
    int c = nt * 16 + li;
    bias[nt] = (c < 64) ? bmu[c] : blv[c - 64];
  }

  f32x4 acc[8];
#pragma unroll
  for (int t = 0; t < 8; ++t) acc[t] = (f32x4){0.f, 0.f, 0.f, 0.f};

#pragma unroll
  for (int kk = 0; kk < 4; ++kk) {
    int ko = kk * 32 + quad * 8;
    bf16x8 a = *(const bf16x8*)&Xl[(m0 + li) * 136 + ko];
    bf16x8 bf[8];
#pragma unroll
    for (int nt = 0; nt < 8; ++nt) bf[nt] = Wf[(kk * 8 + nt) * 64 + lane];
#pragma unroll
    for (int nt = 0; nt < 8; ++nt)
      acc[nt] = __builtin_amdgcn_mfma_f32_16x16x32_bf16(a, bf[nt], acc[nt], 0, 0, 0);
  }
#pragma unroll
  for (int nt = 0; nt < 8; ++nt) {
    int col = nt * 16 + li;
#pragma unroll
    for (int r = 0; r < 4; ++r) {
      int gi = row0 + m0 + quad * 4 + r;
      if (gi < n) {
        float v = acc[nt][r] + bias[nt];
        if (col < 64) out[(size_t)gi * 64 + col] = v;              // mu
        else          out[(size_t)(n + gi) * 64 + (col - 64)] = v; // logvar
      }
    }
  }
}

extern "C" void kernel_launch(void* const* d_in, const int* in_sizes, int n_in,
                              void* d_out, int out_size, void* d_ws, size_t ws_size,
                              hipStream_t stream) {
  const float* x   = (const float*)d_in[0];
  const int*   ei  = (const int*)d_in[1];   // [2, E], row0 = src, row1 = dst
  const float* W1  = (const float*)d_in[3];
  const float* b1  = (const float*)d_in[4];
  const float* Wmu = (const float*)d_in[5];
  const float* bmu = (const float*)d_in[6];
  const float* Wlv = (const float*)d_in[7];
  const float* blv = (const float*)d_in[8];
  float* out = (float*)d_out;

  const int n = in_sizes[0] / 128;
  const int E = in_sizes[1] / 2;

  // workspace layout (float units)
  float* ws = (float*)d_ws;
  size_t p = 0;
  int* cnt    = (int*)(ws + p); p += (size_t)n * CSTRIDE;  // spread counters (64B apart)
  int* ocount = (int*)(ws + p); p += 1;
  p = (p + 3) & ~(size_t)3;  // 16B align
  int* ell    = (int*)(ws + p); p += (size_t)n * ELLK;     // TRANSPOSED: [ELLK][n]
  int2* ovf   = (int2*)(ws + p); p += (size_t)OCAP * 2;
  unsigned* A = (unsigned*)(ws + p); p += (size_t)(n + 1) * 64;  // +1: zero pad row
  unsigned* H = (unsigned*)(ws + p); p += (size_t)(n + 1) * 64;
  unsigned short* Wt1 = (unsigned short*)(ws + p); p += 8192;  // 128x128 bf16 (fragment order)
  unsigned short* Wt2 = (unsigned short*)(ws + p); p += 8192;
  float* dnorm    = (float*)(ws + p); p += n;
  unsigned* mflag = (unsigned*)(ws + p); p += n;

  int nz4  = (n * CSTRIDE) / 4;        // uint4 count for counter zeroing
  int nbz  = (nz4 + 255) / 256;
  int eb   = (E + 1023) / 1024;        // 4 edges per thread
  int gblk = (n + 63) / 64;
  int sblk = (n + 3) / 4;              // one wave per node

  // 1) zero counters/ocount/pad-rows + fragment-ordered weight transpose
  k_setup<<<nbz + 128, 256, 0, stream>>>(W1, Wmu, Wlv, Wt1, Wt2, (uint4*)cnt, ocount,
                                         A, H, nz4, nbz, n);
  // 2) ELL build (transposed planes, 4-deep atomic pipelining)
  k_fill<<<eb, 256, 0, stream>>>(ei, cnt, ell, ovf, ocount, E, n);
  // 3) A = bf16(dis_i * (x @ W1)) pre-scaled; emits dnorm/mflag as side product
  k_gemm1<<<gblk, 256, 0, stream>>>(x, Wt1, cnt, (unsigned short*)A, dnorm, mflag, n);
  // 4) layer 1: H_bar = dis*relu(dis*sum + b1)  (pre-scaled for layer 2)
  k_spmm1<<<sblk, 256, 0, stream>>>(mflag, dnorm, ell, ovf, ocount, A, H,
                                    (const float2*)b1, n);
  // 5) FUSED layer 2 + GEMM2: out = [G@Wmu+bmu | G@Wlv+blv], G stays in LDS
  k_spmm2_gemm2<<<gblk, 256, 0, stream>>>(mflag, dnorm, ell, ovf, ocount, H, Wt2,
                                          bmu, blv, out, n);
}

// Round 7
// 282.018 us; speedup vs baseline: 1.0476x; 1.0022x over previous
//
#include <hip/hip_runtime.h>
#include <hip/hip_cooperative_groups.h>

namespace cg = cooperative_groups;

typedef short bf16x8 __attribute__((ext_vector_type(8)));
typedef float f32x4 __attribute__((ext_vector_type(4)));

#define ELLK 32
#define OCAP 4096
#define CSTRIDE 16  // ints between degree counters (64B apart): no same-line atomic aliasing
#define MGRID 1024  // cooperative grid: 4 blocks/CU x 256 CU (guaranteed by launch_bounds(256,4))

static __device__ __forceinline__ float4 f4zero() { return make_float4(0.f, 0.f, 0.f, 0.f); }

// round-to-nearest-even f32 -> bf16
static __device__ __forceinline__ unsigned short f2bf(float f) {
  unsigned u = __float_as_uint(f);
  u += 0x7FFFu + ((u >> 16) & 1u);
  return (unsigned short)(u >> 16);
}
// packed pair of bf16 (low = first elem) -> float2
static __device__ __forceinline__ float2 bf2x2(unsigned u) {
  float2 r;
  r.x = __uint_as_float(u << 16);
  r.y = __uint_as_float(u & 0xFFFF0000u);
  return r;
}

// ============================ MEGA KERNEL (cooperative) ============================
// phases: [A] zero cnt/ocount/pads + fragment-order weight transpose | sync
//         [B] ELL fill (transposed planes)                           | sync
//         [C] gemm1: A_bar = bf16(dis_i * (x@W1)), emits dnorm/mflag | sync
//         [D] spmm1: H_bar = dis*relu(dis*rowsum(A_bar) + b1)        | sync
//         [E] spmm2+gemm2: out = [G@Wmu+bmu | G@Wlv+blv], G in LDS
__global__ __launch_bounds__(256, 4) void k_mega(
    const float* __restrict__ x, const int* __restrict__ ei,
    const float* __restrict__ W1, const float* __restrict__ Wmu,
    const float* __restrict__ Wlv, const float2* __restrict__ b1,
    const float* __restrict__ bmu, const float* __restrict__ blv,
    float* __restrict__ out, int* __restrict__ cnt, int* __restrict__ ocount,
    int* __restrict__ ell, int2* __restrict__ ovf, unsigned* __restrict__ A,
    unsigned* __restrict__ H, unsigned short* __restrict__ Wt1,
    unsigned short* __restrict__ Wt2, float* __restrict__ dnorm,
    unsigned* __restrict__ mflag, int n, int E, int nz4, int gblk) {
  cg::grid_group grid = cg::this_grid();
  __shared__ unsigned short Xl[64 * 136];
  __shared__ float dnl[64];
  const int tid = threadIdx.x;
  const int gtid = blockIdx.x * 256 + tid;
  const int gth = gridDim.x * 256;
  const int wave = tid >> 6, lane = tid & 63;
  const int li = lane & 15, quad = lane >> 4;
  const int m0 = wave * 16;

  // ---------------- phase A: zero + weight transpose ----------------
  {
    uint4* cntz = (uint4*)cnt;
    for (int i = gtid; i < nz4; i += gth) cntz[i] = make_uint4(0u, 0u, 0u, 0u);
    if (gtid == 0) *ocount = 0;
    if (gtid < 64) A[(size_t)n * 64 + gtid] = 0u;                 // zero pad row (A)
    else if (gtid < 128) H[(size_t)n * 64 + (gtid - 64)] = 0u;    // zero pad row (H)
    for (int id = gtid; id < 32768; id += gth) {
      if (id < 16384) {
        int j = id & 7, ln = (id >> 3) & 63, g = id >> 9;  // g = kk*8+nt
        int kk = g >> 3, nt = g & 7, lli = ln & 15, qq = ln >> 4;
        int nn = nt * 16 + lli, k = kk * 32 + qq * 8 + j;
        Wt1[id] = f2bf(W1[k * 128 + nn]);
      } else {
        int id2 = id - 16384;
        int j = id2 & 7, ln = (id2 >> 3) & 63, g = id2 >> 9;
        int kk = g >> 3, nt = g & 7, lli = ln & 15, qq = ln >> 4;
        int nn = nt * 16 + lli, k = kk * 32 + qq * 8 + j;
        float v = (nn < 64) ? Wmu[k * 64 + nn] : Wlv[k * 64 + (nn - 64)];
        Wt2[id2] = f2bf(v);
      }
    }
  }
  grid.sync();

  // ---------------- phase B: ELL fill ----------------
  for (int e = gtid; e < E; e += gth) {
    int s = ei[e];
    int d = ei[E + e];
    int pos = atomicAdd(&cnt[(size_t)d * CSTRIDE], 1);
    if (pos < ELLK) {
      __builtin_nontemporal_store(s, &ell[(size_t)pos * n + d]);
    } else {
      int o = atomicAdd(ocount, 1);
      if (o < OCAP) ovf[o] = make_int2(d, s);
    }
  }
  grid.sync();

  // ---------------- phase C: gemm1 (fragment-W, pre-scaled output) ----------------
  for (int t = blockIdx.x; t < gblk; t += gridDim.x) {
    const int row0 = t * 64;
#pragma unroll
    for (int i = 0; i < 8; ++i) {
      int idx = tid + i * 256;  // 0..2047
      int r = idx >> 5, c = idx & 31;
      int gi = row0 + r;
      float4 v = (gi < n) ? ((const float4*)x)[(size_t)gi * 32 + c] : f4zero();
      ushort4 p;
      p.x = f2bf(v.x); p.y = f2bf(v.y); p.z = f2bf(v.z); p.w = f2bf(v.w);
      *(ushort4*)&Xl[r * 136 + c * 4] = p;
    }
    if (tid < 64) {  // side product: dnorm/mflag (cnt is L2-hot after fill)
      int gi = row0 + tid;
      float dn = 0.f;
      if (gi < n) {
        int c = cnt[(size_t)gi * CSTRIDE];
        dn = rsqrtf((float)(c + 1));
        dnorm[gi] = dn;
        int mm = (c < ELLK) ? c : ELLK;
        mflag[gi] = (unsigned)mm | ((c > ELLK) ? 0x80000000u : 0u);
      }
      dnl[tid] = dn;
    }
    __syncthreads();

    const bf16x8* Wf = (const bf16x8*)Wt1;
    f32x4 acc[8];
#pragma unroll
    for (int q = 0; q < 8; ++q) acc[q] = (f32x4){0.f, 0.f, 0.f, 0.f};
#pragma unroll
    for (int kk = 0; kk < 4; ++kk) {
      int ko = kk * 32 + quad * 8;
      bf16x8 a = *(const bf16x8*)&Xl[(m0 + li) * 136 + ko];
      bf16x8 bf[8];
#pragma unroll
      for (int nt = 0; nt < 8; ++nt) bf[nt] = Wf[(kk * 8 + nt) * 64 + lane];
#pragma unroll
      for (int nt = 0; nt < 8; ++nt)
        acc[nt] = __builtin_amdgcn_mfma_f32_16x16x32_bf16(a, bf[nt], acc[nt], 0, 0, 0);
    }
    __syncthreads();  // MFMA reads of Xl done
    float dn[4];
#pragma unroll
    for (int r = 0; r < 4; ++r) dn[r] = dnl[m0 + quad * 4 + r];
#pragma unroll
    for (int nt = 0; nt < 8; ++nt)
#pragma unroll
      for (int r = 0; r < 4; ++r)
        Xl[(m0 + quad * 4 + r) * 136 + nt * 16 + li] = f2bf(acc[nt][r] * dn[r]);
    __syncthreads();
    {
      uint4* A4 = (uint4*)A;
#pragma unroll
      for (int i = 0; i < 4; ++i) {
        int idx = tid + i * 256;  // 0..1023
        int r = idx >> 4, c = idx & 15;
        int gi = row0 + r;
        if (gi < n) A4[(size_t)gi * 16 + c] = *(uint4*)&Xl[r * 136 + c * 8];
      }
    }
    __syncthreads();  // protect Xl for next tile
  }
  grid.sync();

  // ---------------- phase D: spmm1 (pure row-sum of pre-scaled A_bar) ----------------
  for (int wid = blockIdx.x * 4 + wave; wid < n; wid += gridDim.x * 4) {
    unsigned mf = mflag[wid];
    int m = (int)(mf & 0xFFFFu);
    float dsd = dnorm[wid];
    float2 acc = bf2x2(A[(size_t)wid * 64 + lane]);  // own row (pre-scaled self term)
    const int* ep = ell + wid;  // plane stride = n
    int nbt = (m + 7) >> 3;
    for (int b = 0; b < nbt; ++b) {
      int j0 = b * 8;
      int idx[8];
#pragma unroll
      for (int k = 0; k < 8; ++k) idx[k] = ep[(size_t)(j0 + k) * n];
#pragma unroll
      for (int k = 0; k < 8; ++k) idx[k] = (j0 + k < m) ? idx[k] : n;  // pads -> zero row
      unsigned u[8];
#pragma unroll
      for (int k = 0; k < 8; ++k) u[k] = A[(size_t)idx[k] * 64 + lane];
#pragma unroll
      for (int k = 0; k < 8; ++k) {
        float2 f = bf2x2(u[k]);
        acc.x += f.x;
        acc.y += f.y;
      }
    }
    if (mf & 0x80000000u) {  // overflow list scan (rare)
      int oc = *ocount;
      if (oc > OCAP) oc = OCAP;
      for (int k = 0; k < oc; ++k) {
        int2 e = ovf[k];
        if (e.x == wid) {
          float2 u0 = bf2x2(A[(size_t)e.y * 64 + lane]);
          acc.x += u0.x;
          acc.y += u0.y;
        }
      }
    }
    float2 b = b1[lane];
    float2 o;
    o.x = dsd * fmaxf(fmaf(dsd, acc.x, b.x), 0.f);
    o.y = dsd * fmaxf(fmaf(dsd, acc.y, b.y), 0.f);
    unsigned pk = (unsigned)f2bf(o.x) | ((unsigned)f2bf(o.y) << 16);
    H[(size_t)wid * 64 + lane] = pk;
  }
  grid.sync();

  // ---------------- phase E: spmm2 + gemm2 (G stays in LDS) ----------------
  for (int t = blockIdx.x; t < gblk; t += gridDim.x) {
    const int row0 = t * 64;
#pragma unroll 1
    for (int i = 0; i < 16; ++i) {
      int nd = row0 + wave * 16 + i;
      unsigned pk = 0u;
      if (nd < n) {
        unsigned mf = mflag[nd];
        int m = (int)(mf & 0xFFFFu);
        float dsd = dnorm[nd];
        float2 acc = bf2x2(H[(size_t)nd * 64 + lane]);  // own row (pre-scaled)
        const int* ep = ell + nd;
        int nbt = (m + 7) >> 3;
        for (int b = 0; b < nbt; ++b) {
          int j0 = b * 8;
          int idx[8];
#pragma unroll
          for (int k = 0; k < 8; ++k) idx[k] = ep[(size_t)(j0 + k) * n];
#pragma unroll
          for (int k = 0; k < 8; ++k) idx[k] = (j0 + k < m) ? idx[k] : n;
          unsigned u[8];
#pragma unroll
          for (int k = 0; k < 8; ++k) u[k] = H[(size_t)idx[k] * 64 + lane];
#pragma unroll
          for (int k = 0; k < 8; ++k) {
            float2 f = bf2x2(u[k]);
            acc.x += f.x;
            acc.y += f.y;
          }
        }
        if (mf & 0x80000000u) {
          int oc = *ocount;
          if (oc > OCAP) oc = OCAP;
          for (int k = 0; k < oc; ++k) {
            int2 e = ovf[k];
            if (e.x == nd) {
              float2 u0 = bf2x2(H[(size_t)e.y * 64 + lane]);
              acc.x += u0.x;
              acc.y += u0.y;
            }
          }
        }
        float2 o;
        o.x = dsd * acc.x;
        o.y = dsd * acc.y;
        pk = (unsigned)f2bf(o.x) | ((unsigned)f2bf(o.y) << 16);
      }
      *(unsigned*)&Xl[(wave * 16 + i) * 136 + 2 * lane] = pk;  // G row -> LDS
    }
    __syncthreads();

    const bf16x8* Wf = (const bf16x8*)Wt2;
    float bias[8];
#pragma unroll
    for (int nt = 0; nt < 8; ++nt) {
      int c = nt * 16 + li;
      bias[nt] = (c < 64) ? bmu[c] : blv[c - 64];
    }
    f32x4 acc[8];
#pragma unroll
    for (int q = 0; q < 8; ++q) acc[q] = (f32x4){0.f, 0.f, 0.f, 0.f};
#pragma unroll
    for (int kk = 0; kk < 4; ++kk) {
      int ko = kk * 32 + quad * 8;
      bf16x8 a = *(const bf16x8*)&Xl[(m0 + li) * 136 + ko];
      bf16x8 bf[8];
#pragma unroll
      for (int nt = 0; nt < 8; ++nt) bf[nt] = Wf[(kk * 8 + nt) * 64 + lane];
#pragma unroll
      for (int nt = 0; nt < 8; ++nt)
        acc[nt] = __builtin_amdgcn_mfma_f32_16x16x32_bf16(a, bf[nt], acc[nt], 0, 0, 0);
    }
#pragma unroll
    for (int nt = 0; nt < 8; ++nt) {
      int col = nt * 16 + li;
#pragma unroll
      for (int r = 0; r < 4; ++r) {
        int gi = row0 + m0 + quad * 4 + r;
        if (gi < n) {
          float v = acc[nt][r] + bias[nt];
          if (col < 64) out[(size_t)gi * 64 + col] = v;              // mu
          else          out[(size_t)(n + gi) * 64 + (col - 64)] = v; // logvar
        }
      }
    }
    __syncthreads();  // protect Xl for next tile
  }
}

// ============================ FALLBACK PATH (round-6 proven, 5 kernels) ============================
__global__ void k_setup(const float* __restrict__ W1, const float* __restrict__ Wmu,
                        const float* __restrict__ Wlv, unsigned short* __restrict__ Wt1,
                        unsigned short* __restrict__ Wt2, uint4* __restrict__ cntz,
                        int* __restrict__ ocount, unsigned* __restrict__ A,
                        unsigned* __restrict__ H, int nz4, int nbz, int n) {
  int b = blockIdx.x;
  if (b < nbz) {
    int i = b * 256 + threadIdx.x;
    if (i < nz4) cntz[i] = make_uint4(0u, 0u, 0u, 0u);
    if (b == 0) {
      int t = threadIdx.x;
      if (t == 0) *ocount = 0;
      if (t < 64) A[(size_t)n * 64 + t] = 0u;
      else if (t < 128) H[(size_t)n * 64 + (t - 64)] = 0u;
    }
  } else {
    int id = (b - nbz) * 256 + threadIdx.x;  // 0..32767
    if (id < 16384) {
      int j = id & 7, lane = (id >> 3) & 63, g = id >> 9;
      int kk = g >> 3, nt = g & 7, li = lane & 15, quad = lane >> 4;
      int nn = nt * 16 + li, k = kk * 32 + quad * 8 + j;
      Wt1[id] = f2bf(W1[k * 128 + nn]);
    } else {
      int id2 = id - 16384;
      int j = id2 & 7, lane = (id2 >> 3) & 63, g = id2 >> 9;
      int kk = g >> 3, nt = g & 7, li = lane & 15, quad = lane >> 4;
      int nn = nt * 16 + li, k = kk * 32 + quad * 8 + j;
      float v = (nn < 64) ? Wmu[k * 64 + nn] : Wlv[k * 64 + (nn - 64)];
      Wt2[id2] = f2bf(v);
    }
  }
}

__global__ void k_fill(const int* __restrict__ ei, int* __restrict__ cnt,
                       int* __restrict__ ell, int2* __restrict__ ovf,
                       int* __restrict__ ocount, int E, int n) {
  int e0 = blockIdx.x * 1024 + threadIdx.x;
  int ss[4], dd[4], pos[4];
  bool ok[4];
#pragma unroll
  for (int k = 0; k < 4; ++k) {
    int e = e0 + k * 256;
    ok[k] = (e < E);
    ss[k] = ok[k] ? ei[e] : 0;
    dd[k] = ok[k] ? ei[E + e] : 0;
  }
#pragma unroll
  for (int k = 0; k < 4; ++k)
    pos[k] = ok[k] ? atomicAdd(&cnt[(size_t)dd[k] * CSTRIDE], 1) : ELLK;
#pragma unroll
  for (int k = 0; k < 4; ++k) {
    if (!ok[k]) continue;
    if (pos[k] < ELLK) {
      __builtin_nontemporal_store(ss[k], &ell[(size_t)pos[k] * n + dd[k]]);
    } else {
      int o = atomicAdd(ocount, 1);
      if (o < OCAP) ovf[o] = make_int2(dd[k], ss[k]);
    }
  }
}

__global__ __launch_bounds__(256, 4) void k_gemm1(
    const float* __restrict__ x, const unsigned short* __restrict__ Wt,
    const int* __restrict__ cnt, unsigned short* __restrict__ A,
    float* __restrict__ dnorm, unsigned* __restrict__ mflag, int n) {
  __shared__ unsigned short Xl[64 * 136];
  __shared__ float dnl[64];
  const int tid = threadIdx.x;
  const int row0 = blockIdx.x * 64;
  {
#pragma unroll
    for (int i = 0; i < 8; ++i) {
      int idx = tid + i * 256;
      int r = idx >> 5, c = idx & 31;
      int gi = row0 + r;
      float4 v = (gi < n) ? ((const float4*)x)[(size_t)gi * 32 + c] : f4zero();
      ushort4 p;
      p.x = f2bf(v.x); p.y = f2bf(v.y); p.z = f2bf(v.z); p.w = f2bf(v.w);
      *(ushort4*)&Xl[r * 136 + c * 4] = p;
    }
  }
  if (tid < 64) {
    int gi = row0 + tid;
    float dn = 0.f;
    if (gi < n) {
      int c = cnt[(size_t)gi * CSTRIDE];
      dn = rsqrtf((float)(c + 1));
      dnorm[gi] = dn;
      int mm = (c < ELLK) ? c : ELLK;
      mflag[gi] = (unsigned)mm | ((c > ELLK) ? 0x80000000u : 0u);
    }
    dnl[tid] = dn;
  }
  __syncthreads();

  const int wave = tid >> 6, lane = tid & 63;
  const int li = lane & 15, quad = lane >> 4;
  const int m0 = wave * 16;
  const bf16x8* Wf = (const bf16x8*)Wt;
  f32x4 acc[8];
#pragma unroll
  for (int t = 0; t < 8; ++t) acc[t] = (f32x4){0.f, 0.f, 0.f, 0.f};
#pragma unroll
  for (int kk = 0; kk < 4; ++kk) {
    int ko = kk * 32 + quad * 8;
    bf16x8 a = *(const bf16x8*)&Xl[(m0 + li) * 136 + ko];
    bf16x8 bf[8];
#pragma unroll
    for (int nt = 0; nt < 8; ++nt) bf[nt] = Wf[(kk * 8 + nt) * 64 + lane];
#pragma unroll
    for (int nt = 0; nt < 8; ++nt)
      acc[nt] = __builtin_amdgcn_mfma_f32_16x16x32_bf16(a, bf[nt], acc[nt], 0, 0, 0);
  }
  __syncthreads();
  float dn[4];
#pragma unroll
  for (int r = 0; r < 4; ++r) dn[r] = dnl[m0 + quad * 4 + r];
#pragma unroll
  for (int nt = 0; nt < 8; ++nt)
#pragma unroll
    for (int r = 0; r < 4; ++r)
      Xl[(m0 + quad * 4 + r) * 136 + nt * 16 + li] = f2bf(acc[nt][r] * dn[r]);
  __syncthreads();
  {
    uint4* A4 = (uint4*)A;
#pragma unroll
    for (int i = 0; i < 4; ++i) {
      int idx = tid + i * 256;
      int r = idx >> 4, c = idx & 15;
      int gi = row0 + r;
      if (gi < n) A4[(size_t)gi * 16 + c] = *(uint4*)&Xl[r * 136 + c * 8];
    }
  }
}

__global__ __launch_bounds__(256) void k_spmm1(
    const unsigned* __restrict__ mflag, const float* __restrict__ dnorm,
    const int* __restrict__ ell, const int2* __restrict__ ovf,
    const int* __restrict__ ocount, const unsigned* __restrict__ S,
    unsigned* __restrict__ D, const float2* __restrict__ bias, int n) {
  int wid = (blockIdx.x * blockDim.x + threadIdx.x) >> 6;
  if (wid >= n) return;
  int lane = threadIdx.x & 63;
  unsigned mf = mflag[wid];
  int m = (int)(mf & 0xFFFFu);
  float dsd = dnorm[wid];
  float2 acc = bf2x2(S[(size_t)wid * 64 + lane]);
  const int* ep = ell + wid;
  int nbt = (m + 7) >> 3;
  for (int b = 0; b < nbt; ++b) {
    int j0 = b * 8;
    int idx[8];
#pragma unroll
    for (int k = 0; k < 8; ++k) idx[k] = ep[(size_t)(j0 + k) * n];
#pragma unroll
    for (int k = 0; k < 8; ++k) idx[k] = (j0 + k < m) ? idx[k] : n;
    unsigned u[8];
#pragma unroll
    for (int k = 0; k < 8; ++k) u[k] = S[(size_t)idx[k] * 64 + lane];
#pragma unroll
    for (int k = 0; k < 8; ++k) {
      float2 f = bf2x2(u[k]);
      acc.x += f.x;
      acc.y += f.y;
    }
  }
  if (mf & 0x80000000u) {
    int oc = *ocount;
    if (oc > OCAP) oc = OCAP;
    for (int k = 0; k < oc; ++k) {
      int2 e = ovf[k];
      if (e.x == wid) {
        float2 u0 = bf2x2(S[(size_t)e.y * 64 + lane]);
        acc.x += u0.x;
        acc.y += u0.y;
      }
    }
  }
  float2 b = bias[lane];
  float2 o;
  o.x = dsd * fmaxf(fmaf(dsd, acc.x, b.x), 0.f);
  o.y = dsd * fmaxf(fmaf(dsd, acc.y, b.y), 0.f);
  unsigned pk = (unsigned)f2bf(o.x) | ((unsigned)f2bf(o.y) << 16);
  D[(size_t)wid * 64 + lane] = pk;
}

__global__ __launch_bounds__(256, 4) void k_spmm2_gemm2(
    const unsigned* __restrict__ mflag, const float* __restrict__ dnorm,
    const int* __restrict__ ell, const int2* __restrict__ ovf,
    const int* __restrict__ ocount, const unsigned* __restrict__ H,
    const unsigned short* __restrict__ Wt, const float* __restrict__ bmu,
    const float* __restrict__ blv, float* __restrict__ out, int n) {
  __shared__ unsigned short Xl[64 * 136];
  const int tid = threadIdx.x;
  const int wave = tid >> 6, lane = tid & 63;
  const int row0 = blockIdx.x * 64;
#pragma unroll 1
  for (int i = 0; i < 16; ++i) {
    int nd = row0 + wave * 16 + i;
    unsigned pk = 0u;
    if (nd < n) {
      unsigned mf = mflag[nd];
      int m = (int)(mf & 0xFFFFu);
      float dsd = dnorm[nd];
      float2 acc = bf2x2(H[(size_t)nd * 64 + lane]);
      const int* ep = ell + nd;
      int nbt = (m + 7) >> 3;
      for (int b = 0; b < nbt; ++b) {
        int j0 = b * 8;
        int idx[8];
#pragma unroll
        for (int k = 0; k < 8; ++k) idx[k] = ep[(size_t)(j0 + k) * n];
#pragma unroll
        for (int k = 0; k < 8; ++k) idx[k] = (j0 + k < m) ? idx[k] : n;
        unsigned u[8];
#pragma unroll
        for (int k = 0; k < 8; ++k) u[k] = H[(size_t)idx[k] * 64 + lane];
#pragma unroll
        for (int k = 0; k < 8; ++k) {
          float2 f = bf2x2(u[k]);
          acc.x += f.x;
          acc.y += f.y;
        }
      }
      if (mf & 0x80000000u) {
        int oc = *ocount;
        if (oc > OCAP) oc = OCAP;
        for (int k = 0; k < oc; ++k) {
          int2 e = ovf[k];
          if (e.x == nd) {
            float2 u0 = bf2x2(H[(size_t)e.y * 64 + lane]);
            acc.x += u0.x;
            acc.y += u0.y;
          }
        }
      }
      float2 o;
      o.x = dsd * acc.x;
      o.y = dsd * acc.y;
      pk = (unsigned)f2bf(o.x) | ((unsigned)f2bf(o.y) << 16);
    }
    *(unsigned*)&Xl[(wave * 16 + i) * 136 + 2 * lane] = pk;
  }
  __syncthreads();

  const int li = lane & 15, quad = lane >> 4;
  const int m0 = wave * 16;
  const bf16x8* Wf = (const bf16x8*)Wt;
  float bias[8];
#pragma unroll
  for (int nt = 0; nt < 8; ++nt) {
    int c = nt * 16 + li;
    bias[nt] = (c < 64) ? bmu[c] : blv[c - 64];
  }
  f32x4 acc[8];
#pragma unroll
  for (int t = 0; t < 8; ++t) acc[t] = (f32x4){0.f, 0.f, 0.f, 0.f};
#pragma unroll
  for (int kk = 0; kk < 4; ++kk) {
    int ko = kk * 32 + quad * 8;
    bf16x8 a = *(const bf16x8*)&Xl[(m0 + li) * 136 + ko];
    bf16x8 bf[8];
#pragma unroll
    for (int nt = 0; nt < 8; ++nt) bf[nt] = Wf[(kk * 8 + nt) * 64 + lane];
#pragma unroll
    for (int nt = 0; nt < 8; ++nt)
      acc[nt] = __builtin_amdgcn_mfma_f32_16x16x32_bf16(a, bf[nt], acc[nt], 0, 0, 0);
  }
#pragma unroll
  for (int nt = 0; nt < 8; ++nt) {
    int col = nt * 16 + li;
#pragma unroll
    for (int r = 0; r < 4; ++r) {
      int gi = row0 + m0 + quad * 4 + r;
      if (gi < n) {
        float v = acc[nt][r] + bias[nt];
        if (col < 64) out[(size_t)gi * 64 + col] = v;
        else          out[(size_t)(n + gi) * 64 + (col - 64)] = v;
      }
    }
  }
}

extern "C" void kernel_launch(void* const* d_in, const int* in_sizes, int n_in,
                              void* d_out, int out_size, void* d_ws, size_t ws_size,
                              hipStream_t stream) {
  const float* x   = (const float*)d_in[0];
  const int*   ei  = (const int*)d_in[1];   // [2, E], row0 = src, row1 = dst
  const float* W1  = (const float*)d_in[3];
  const float* b1  = (const float*)d_in[4];
  const float* Wmu = (const float*)d_in[5];
  const float* bmu = (const float*)d_in[6];
  const float* Wlv = (const float*)d_in[7];
  const float* blv = (const float*)d_in[8];
  float* out = (float*)d_out;

  const int n = in_sizes[0] / 128;
  const int E = in_sizes[1] / 2;

  // workspace layout (float units)
  float* ws = (float*)d_ws;
  size_t p = 0;
  int* cnt    = (int*)(ws + p); p += (size_t)n * CSTRIDE;  // spread counters (64B apart)
  int* ocount = (int*)(ws + p); p += 1;
  p = (p + 3) & ~(size_t)3;  // 16B align
  int* ell    = (int*)(ws + p); p += (size_t)n * ELLK;     // TRANSPOSED: [ELLK][n]
  int2* ovf   = (int2*)(ws + p); p += (size_t)OCAP * 2;
  unsigned* A = (unsigned*)(ws + p); p += (size_t)(n + 1) * 64;  // +1: zero pad row
  unsigned* H = (unsigned*)(ws + p); p += (size_t)(n + 1) * 64;
  unsigned short* Wt1 = (unsigned short*)(ws + p); p += 8192;  // 128x128 bf16 (fragment order)
  unsigned short* Wt2 = (unsigned short*)(ws + p); p += 8192;
  float* dnorm    = (float*)(ws + p); p += n;
  unsigned* mflag = (unsigned*)(ws + p); p += n;

  int nz4  = (n * CSTRIDE) / 4;
  int nbz  = (nz4 + 255) / 256;
  int eb   = (E + 1023) / 1024;
  int gblk = (n + 63) / 64;
  int sblk = (n + 3) / 4;

  static int coop = -1;
  if (coop < 0) {
    int dev = 0, v = 0;
    (void)hipGetDevice(&dev);
    if (hipDeviceGetAttribute(&v, hipDeviceAttributeCooperativeLaunch, dev) != hipSuccess) v = 0;
    coop = v;
  }

  if (coop) {
    // single cooperative launch: 4 grid syncs replace 4 inter-kernel gaps (~15 us each)
    const float2* b1f2 = (const float2*)b1;
    void* args[] = {(void*)&x,   (void*)&ei,   (void*)&W1,  (void*)&Wmu, (void*)&Wlv,
                    (void*)&b1f2,(void*)&bmu,  (void*)&blv, (void*)&out, (void*)&cnt,
                    (void*)&ocount, (void*)&ell, (void*)&ovf, (void*)&A, (void*)&H,
                    (void*)&Wt1, (void*)&Wt2, (void*)&dnorm, (void*)&mflag,
                    (void*)&n, (void*)&E, (void*)&nz4, (void*)&gblk};
    hipError_t err = hipLaunchCooperativeKernel((void*)k_mega, dim3(MGRID), dim3(256),
                                                args, 0, stream);
    if (err == hipSuccess) return;
    (void)hipGetLastError();  // clear; fall through to 5-kernel path
    coop = 0;
  }

  // fallback: round-6 proven pipeline
  k_setup<<<nbz + 128, 256, 0, stream>>>(W1, Wmu, Wlv, Wt1, Wt2, (uint4*)cnt, ocount,
                                         A, H, nz4, nbz, n);
  k_fill<<<eb, 256, 0, stream>>>(ei, cnt, ell, ovf, ocount, E, n);
  k_gemm1<<<gblk, 256, 0, stream>>>(x, Wt1, cnt, (unsigned short*)A, dnorm, mflag, n);
  k_spmm1<<<sblk, 256, 0, stream>>>(mflag, dnorm, ell, ovf, ocount, A, H,
                                    (const float2*)b1, n);
  k_spmm2_gemm2<<<gblk, 256, 0, stream>>>(mflag, dnorm, ell, ovf, ocount, H, Wt2,
                                          bmu, blv, out, n);
}

// Round 8
// 275.362 us; speedup vs baseline: 1.0730x; 1.0242x over previous
//
#include <hip/hip_runtime.h>

typedef short bf16x8 __attribute__((ext_vector_type(8)));
typedef float f32x4 __attribute__((ext_vector_type(4)));

#define ELLK 32
#define OCAP 4096
#define CSTRIDE 16  // ints between degree counters (64B apart): no same-line atomic aliasing

static __device__ __forceinline__ float4 f4zero() { return make_float4(0.f, 0.f, 0.f, 0.f); }

// round-to-nearest-even f32 -> bf16
static __device__ __forceinline__ unsigned short f2bf(float f) {
  unsigned u = __float_as_uint(f);
  u += 0x7FFFu + ((u >> 16) & 1u);
  return (unsigned short)(u >> 16);
}
// packed pair of bf16 (low = first elem) -> float2
static __device__ __forceinline__ float2 bf2x2(unsigned u) {
  float2 r;
  r.x = __uint_as_float(u << 16);
  r.y = __uint_as_float(u & 0xFFFF0000u);
  return r;
}

// ---------- setup: zero counters/ocount/pad-rows + weights -> bf16 in MFMA-FRAGMENT order ----------
// Wt[frag]: id = ((kk*8+nt)*64 + lane)*8 + j  ->  W[k = kk*32+quad*8+j][nn = nt*16+li]
__global__ void k_setup(const float* __restrict__ W1, const float* __restrict__ Wmu,
                        const float* __restrict__ Wlv, unsigned short* __restrict__ Wt1,
                        unsigned short* __restrict__ Wt2, uint4* __restrict__ cntz,
                        int* __restrict__ ocount, unsigned* __restrict__ A,
                        unsigned* __restrict__ H, int nz4, int nbz, int n) {
  int b = blockIdx.x;
  if (b < nbz) {
    int i = b * 256 + threadIdx.x;
    if (i < nz4) cntz[i] = make_uint4(0u, 0u, 0u, 0u);
    if (b == 0) {
      int t = threadIdx.x;
      if (t == 0) *ocount = 0;
      if (t < 64) A[(size_t)n * 64 + t] = 0u;               // zero pad row (A)
      else if (t < 128) H[(size_t)n * 64 + (t - 64)] = 0u;  // zero pad row (H)
    }
  } else {
    int id = (b - nbz) * 256 + threadIdx.x;  // 0..32767
    if (id < 16384) {
      int j = id & 7, lane = (id >> 3) & 63, g = id >> 9;  // g = kk*8+nt
      int kk = g >> 3, nt = g & 7, li = lane & 15, quad = lane >> 4;
      int nn = nt * 16 + li, k = kk * 32 + quad * 8 + j;
      Wt1[id] = f2bf(W1[k * 128 + nn]);
    } else {
      int id2 = id - 16384;
      int j = id2 & 7, lane = (id2 >> 3) & 63, g = id2 >> 9;
      int kk = g >> 3, nt = g & 7, li = lane & 15, quad = lane >> 4;
      int nn = nt * 16 + li, k = kk * 32 + quad * 8 + j;
      float v = (nn < 64) ? Wmu[k * 64 + nn] : Wlv[k * 64 + (nn - 64)];
      Wt2[id2] = f2bf(v);
    }
  }
}

// ---------- ELL fill (TRANSPOSED layout ell[pos][n]): 4 edges/thread ----------
// plain cached stores: plane working set ~1.6MB/XCD fits L2 -> write-combine (~4 stores/line)
__global__ void k_fill(const int* __restrict__ ei, int* __restrict__ cnt,
                       int* __restrict__ ell, int2* __restrict__ ovf,
                       int* __restrict__ ocount, int E, int n) {
  int e0 = blockIdx.x * 1024 + threadIdx.x;
  int ss[4], dd[4], pos[4];
  bool ok[4];
#pragma unroll
  for (int k = 0; k < 4; ++k) {
    int e = e0 + k * 256;
    ok[k] = (e < E);
    ss[k] = ok[k] ? ei[e] : 0;
    dd[k] = ok[k] ? ei[E + e] : 0;
  }
#pragma unroll
  for (int k = 0; k < 4; ++k)
    pos[k] = ok[k] ? atomicAdd(&cnt[(size_t)dd[k] * CSTRIDE], 1) : ELLK;
#pragma unroll
  for (int k = 0; k < 4; ++k) {
    if (!ok[k]) continue;
    if (pos[k] < ELLK) {
      ell[(size_t)pos[k] * n + dd[k]] = ss[k];  // cached store -> L2 write-combine
    } else {
      int o = atomicAdd(ocount, 1);
      if (o < OCAP) ovf[o] = make_int2(dd[k], ss[k]);
    }
  }
}

// ---------- GEMM1 (MFMA, fragment-W): A = bf16(dis_i * (x @ W1)); emits dnorm/mflag ----------
__global__ __launch_bounds__(256, 4) void k_gemm1(
    const float* __restrict__ x, const unsigned short* __restrict__ Wt,
    const int* __restrict__ cnt, unsigned short* __restrict__ A,
    float* __restrict__ dnorm, unsigned* __restrict__ mflag, int n) {
  __shared__ unsigned short Xl[64 * 136];
  __shared__ float dnl[64];
  const int tid = threadIdx.x;
  const int row0 = blockIdx.x * 64;
  {
#pragma unroll
    for (int i = 0; i < 8; ++i) {
      int idx = tid + i * 256;  // 0..2047
      int r = idx >> 5, c = idx & 31;
      int gi = row0 + r;
      float4 v = (gi < n) ? ((const float4*)x)[(size_t)gi * 32 + c] : f4zero();
      ushort4 p;
      p.x = f2bf(v.x); p.y = f2bf(v.y); p.z = f2bf(v.z); p.w = f2bf(v.w);
      *(ushort4*)&Xl[r * 136 + c * 4] = p;
    }
  }
  if (tid < 64) {  // side product: dnorm/mflag (cnt is L2-hot after fill)
    int gi = row0 + tid;
    float dn = 0.f;
    if (gi < n) {
      int c = cnt[(size_t)gi * CSTRIDE];
      dn = rsqrtf((float)(c + 1));
      dnorm[gi] = dn;
      int mm = (c < ELLK) ? c : ELLK;
      mflag[gi] = (unsigned)mm | ((c > ELLK) ? 0x80000000u : 0u);
    }
    dnl[tid] = dn;
  }
  __syncthreads();

  const int wave = tid >> 6, lane = tid & 63;
  const int li = lane & 15, quad = lane >> 4;
  const int m0 = wave * 16;
  const bf16x8* Wf = (const bf16x8*)Wt;
  f32x4 acc[8];
#pragma unroll
  for (int t = 0; t < 8; ++t) acc[t] = (f32x4){0.f, 0.f, 0.f, 0.f};
#pragma unroll
  for (int kk = 0; kk < 4; ++kk) {
    int ko = kk * 32 + quad * 8;
    bf16x8 a = *(const bf16x8*)&Xl[(m0 + li) * 136 + ko];
    bf16x8 bf[8];
#pragma unroll
    for (int nt = 0; nt < 8; ++nt) bf[nt] = Wf[(kk * 8 + nt) * 64 + lane];
#pragma unroll
    for (int nt = 0; nt < 8; ++nt)
      acc[nt] = __builtin_amdgcn_mfma_f32_16x16x32_bf16(a, bf[nt], acc[nt], 0, 0, 0);
  }
  __syncthreads();  // MFMA reads of Xl done
  float dn[4];
#pragma unroll
  for (int r = 0; r < 4; ++r) dn[r] = dnl[m0 + quad * 4 + r];
#pragma unroll
  for (int nt = 0; nt < 8; ++nt)
#pragma unroll
    for (int r = 0; r < 4; ++r)
      Xl[(m0 + quad * 4 + r) * 136 + nt * 16 + li] = f2bf(acc[nt][r] * dn[r]);
  __syncthreads();
  {
    uint4* A4 = (uint4*)A;
#pragma unroll
    for (int i = 0; i < 4; ++i) {
      int idx = tid + i * 256;  // 0..1023
      int r = idx >> 4, c = idx & 15;
      int gi = row0 + r;
      if (gi < n) A4[(size_t)gi * 16 + c] = *(uint4*)&Xl[r * 136 + c * 8];
    }
  }
}

// ---------- SpMM layer 1: one wave/node, pure row-sum of pre-scaled A_bar ----------
__global__ __launch_bounds__(256) void k_spmm1(
    const unsigned* __restrict__ mflag, const float* __restrict__ dnorm,
    const int* __restrict__ ell, const int2* __restrict__ ovf,
    const int* __restrict__ ocount, const unsigned* __restrict__ S,
    unsigned* __restrict__ D, const float2* __restrict__ bias, int n) {
  int wid = (blockIdx.x * blockDim.x + threadIdx.x) >> 6;
  if (wid >= n) return;
  int lane = threadIdx.x & 63;
  unsigned mf = mflag[wid];
  int m = (int)(mf & 0xFFFFu);
  float dsd = dnorm[wid];
  float2 acc = bf2x2(S[(size_t)wid * 64 + lane]);  // own row (pre-scaled self term)
  const int* ep = ell + wid;  // plane stride = n
  int nbt = (m + 7) >> 3;
  for (int b = 0; b < nbt; ++b) {
    int j0 = b * 8;
    int idx[8];
#pragma unroll
    for (int k = 0; k < 8; ++k) idx[k] = ep[(size_t)(j0 + k) * n];
#pragma unroll
    for (int k = 0; k < 8; ++k) idx[k] = (j0 + k < m) ? idx[k] : n;  // pads -> zero row
    unsigned u[8];
#pragma unroll
    for (int k = 0; k < 8; ++k) u[k] = S[(size_t)idx[k] * 64 + lane];
#pragma unroll
    for (int k = 0; k < 8; ++k) {
      float2 f = bf2x2(u[k]);
      acc.x += f.x;
      acc.y += f.y;
    }
  }
  if (mf & 0x80000000u) {  // overflow list scan (rare)
    int oc = *ocount;
    if (oc > OCAP) oc = OCAP;
    for (int k = 0; k < oc; ++k) {
      int2 e = ovf[k];
      if (e.x == wid) {
        float2 u0 = bf2x2(S[(size_t)e.y * 64 + lane]);
        acc.x += u0.x;
        acc.y += u0.y;
      }
    }
  }
  float2 b = bias[lane];
  float2 o;
  o.x = dsd * fmaxf(fmaf(dsd, acc.x, b.x), 0.f);
  o.y = dsd * fmaxf(fmaf(dsd, acc.y, b.y), 0.f);
  unsigned pk = (unsigned)f2bf(o.x) | ((unsigned)f2bf(o.y) << 16);
  D[(size_t)wid * 64 + lane] = pk;
}

// ---------- FUSED SpMM layer 2 + GEMM2: G stays in LDS ----------
// phase 1: each wave aggregates 16 nodes as TWO interleaved streams (ii, ii+8):
//          16 gathers in flight/wave, half the serial node chain (fixes 2.5 vs 3.7 TB/s gap)
// phase 2: MFMA with fragment-W: out = [G@Wmu+bmu | G@Wlv+blv]
__global__ __launch_bounds__(256, 4) void k_spmm2_gemm2(
    const unsigned* __restrict__ mflag, const float* __restrict__ dnorm,
    const int* __restrict__ ell, const int2* __restrict__ ovf,
    const int* __restrict__ ocount, const unsigned* __restrict__ H,
    const unsigned short* __restrict__ Wt, const float* __restrict__ bmu,
    const float* __restrict__ blv, float* __restrict__ out, int n) {
  __shared__ unsigned short Xl[64 * 136];
  const int tid = threadIdx.x;
  const int wave = tid >> 6, lane = tid & 63;
  const int row0 = blockIdx.x * 64;

#pragma unroll 1
  for (int ii = 0; ii < 8; ++ii) {
    int ndA = row0 + wave * 16 + ii;
    int ndB = ndA + 8;
    bool okA = (ndA < n), okB = (ndB < n);
    unsigned mfA = okA ? mflag[ndA] : 0u;
    unsigned mfB = okB ? mflag[ndB] : 0u;
    int mA = (int)(mfA & 0xFFFFu), mB = (int)(mfB & 0xFFFFu);
    float dsA = okA ? dnorm[ndA] : 0.f;
    float dsB = okB ? dnorm[ndB] : 0.f;
    float2 accA = okA ? bf2x2(H[(size_t)ndA * 64 + lane]) : make_float2(0.f, 0.f);
    float2 accB = okB ? bf2x2(H[(size_t)ndB * 64 + lane]) : make_float2(0.f, 0.f);
    const int* epA = ell + (okA ? ndA : 0);
    const int* epB = ell + (okB ? ndB : 0);
    int nbtA = (mA + 7) >> 3, nbtB = (mB + 7) >> 3;
    int nbt = nbtA > nbtB ? nbtA : nbtB;
    for (int b = 0; b < nbt; ++b) {
      int j0 = b * 8;
      int ia[8], ib[8];
#pragma unroll
      for (int k = 0; k < 8; ++k) ia[k] = epA[(size_t)(j0 + k) * n];
#pragma unroll
      for (int k = 0; k < 8; ++k) ib[k] = epB[(size_t)(j0 + k) * n];
#pragma unroll
      for (int k = 0; k < 8; ++k) ia[k] = (j0 + k < mA) ? ia[k] : n;  // pads -> zero row
#pragma unroll
      for (int k = 0; k < 8; ++k) ib[k] = (j0 + k < mB) ? ib[k] : n;
      unsigned ua[8], ub[8];
#pragma unroll
      for (int k = 0; k < 8; ++k) ua[k] = H[(size_t)ia[k] * 64 + lane];
#pragma unroll
      for (int k = 0; k < 8; ++k) ub[k] = H[(size_t)ib[k] * 64 + lane];
#pragma unroll
      for (int k = 0; k < 8; ++k) {
        float2 f = bf2x2(ua[k]);
        accA.x += f.x;
        accA.y += f.y;
      }
#pragma unroll
      for (int k = 0; k < 8; ++k) {
        float2 f = bf2x2(ub[k]);
        accB.x += f.x;
        accB.y += f.y;
      }
    }
    if ((mfA | mfB) & 0x80000000u) {  // overflow list scan (rare)
      int oc = *ocount;
      if (oc > OCAP) oc = OCAP;
      for (int k = 0; k < oc; ++k) {
        int2 e = ovf[k];
        if (okA && e.x == ndA) {
          float2 u0 = bf2x2(H[(size_t)e.y * 64 + lane]);
          accA.x += u0.x;
          accA.y += u0.y;
        }
        if (okB && e.x == ndB) {
          float2 u0 = bf2x2(H[(size_t)e.y * 64 + lane]);
          accB.x += u0.x;
          accB.y += u0.y;
        }
      }
    }
    unsigned pkA = 0u, pkB = 0u;
    if (okA) {
      float2 o;
      o.x = dsA * accA.x;
      o.y = dsA * accA.y;
      pkA = (unsigned)f2bf(o.x) | ((unsigned)f2bf(o.y) << 16);
    }
    if (okB) {
      float2 o;
      o.x = dsB * accB.x;
      o.y = dsB * accB.y;
      pkB = (unsigned)f2bf(o.x) | ((unsigned)f2bf(o.y) << 16);
    }
    *(unsigned*)&Xl[(wave * 16 + ii) * 136 + 2 * lane] = pkA;      // G row ii  -> LDS
    *(unsigned*)&Xl[(wave * 16 + ii + 8) * 136 + 2 * lane] = pkB;  // G row ii+8 -> LDS
  }
  __syncthreads();

  const int li = lane & 15, quad = lane >> 4;
  const int m0 = wave * 16;
  const bf16x8* Wf = (const bf16x8*)Wt;
  float bias[8];
#pragma unroll
  for (int nt = 0; nt < 8; ++nt) {
    int c = nt * 16 + li;
    bias[nt] = (c < 64) ? bmu[c] : blv[c - 64];
  }
  f32x4 acc[8];
#pragma unroll
  for (int t = 0; t < 8; ++t) acc[t] = (f32x4){0.f, 0.f, 0.f, 0.f};
#pragma unroll
  for (int kk = 0; kk < 4; ++kk) {
    int ko = kk * 32 + quad * 8;
    bf16x8 a = *(const bf16x8*)&Xl[(m0 + li) * 136 + ko];
    bf16x8 bf[8];
#pragma unroll
    for (int nt = 0; nt < 8; ++nt) bf[nt] = Wf[(kk * 8 + nt) * 64 + lane];
#pragma unroll
    for (int nt = 0; nt < 8; ++nt)
      acc[nt] = __builtin_amdgcn_mfma_f32_16x16x32_bf16(a, bf[nt], acc[nt], 0, 0, 0);
  }
#pragma unroll
  for (int nt = 0; nt < 8; ++nt) {
    int col = nt * 16 + li;
#pragma unroll
    for (int r = 0; r < 4; ++r) {
      int gi = row0 + m0 + quad * 4 + r;
      if (gi < n) {
        float v = acc[nt][r] + bias[nt];
        if (col < 64) out[(size_t)gi * 64 + col] = v;              // mu
        else          out[(size_t)(n + gi) * 64 + (col - 64)] = v; // logvar
      }
    }
  }
}

extern "C" void kernel_launch(void* const* d_in, const int* in_sizes, int n_in,
                              void* d_out, int out_size, void* d_ws, size_t ws_size,
                              hipStream_t stream) {
  const float* x   = (const float*)d_in[0];
  const int*   ei  = (const int*)d_in[1];   // [2, E], row0 = src, row1 = dst
  const float* W1  = (const float*)d_in[3];
  const float* b1  = (const float*)d_in[4];
  const float* Wmu = (const float*)d_in[5];
  const float* bmu = (const float*)d_in[6];
  const float* Wlv = (const float*)d_in[7];
  const float* blv = (const float*)d_in[8];
  float* out = (float*)d_out;

  const int n = in_sizes[0] / 128;
  const int E = in_sizes[1] / 2;

  // workspace layout (float units)
  float* ws = (float*)d_ws;
  size_t p = 0;
  int* cnt    = (int*)(ws + p); p += (size_t)n * CSTRIDE;  // spread counters (64B apart)
  int* ocount = (int*)(ws + p); p += 1;
  p = (p + 3) & ~(size_t)3;  // 16B align
  int* ell    = (int*)(ws + p); p += (size_t)n * ELLK;     // TRANSPOSED: [ELLK][n]
  int2* ovf   = (int2*)(ws + p); p += (size_t)OCAP * 2;
  unsigned* A = (unsigned*)(ws + p); p += (size_t)(n + 1) * 64;  // +1: zero pad row
  unsigned* H = (unsigned*)(ws + p); p += (size_t)(n + 1) * 64;
  unsigned short* Wt1 = (unsigned short*)(ws + p); p += 8192;  // 128x128 bf16 (fragment order)
  unsigned short* Wt2 = (unsigned short*)(ws + p); p += 8192;
  float* dnorm    = (float*)(ws + p); p += n;
  unsigned* mflag = (unsigned*)(ws + p); p += n;

  int nz4  = (n * CSTRIDE) / 4;
  int nbz  = (nz4 + 255) / 256;
  int eb   = (E + 1023) / 1024;
  int gblk = (n + 63) / 64;
  int sblk = (n + 3) / 4;

  // 1) zero counters/ocount/pad-rows + fragment-ordered weight transpose
  k_setup<<<nbz + 128, 256, 0, stream>>>(W1, Wmu, Wlv, Wt1, Wt2, (uint4*)cnt, ocount,
                                         A, H, nz4, nbz, n);
  // 2) ELL build (transposed planes, cached stores for L2 write-combine)
  k_fill<<<eb, 256, 0, stream>>>(ei, cnt, ell, ovf, ocount, E, n);
  // 3) A = bf16(dis_i * (x @ W1)) pre-scaled; emits dnorm/mflag as side product
  k_gemm1<<<gblk, 256, 0, stream>>>(x, Wt1, cnt, (unsigned short*)A, dnorm, mflag, n);
  // 4) layer 1: H_bar = dis*relu(dis*sum + b1)  (pre-scaled for layer 2)
  k_spmm1<<<sblk, 256, 0, stream>>>(mflag, dnorm, ell, ovf, ocount, A, H,
                                    (const float2*)b1, n);
  // 5) FUSED layer 2 + GEMM2 (2-stream phase-1): out = [G@Wmu+bmu | G@Wlv+blv]
  k_spmm2_gemm2<<<gblk, 256, 0, stream>>>(mflag, dnorm, ell, ovf, ocount, H, Wt2,
                                          bmu, blv, out, n);
}

// Round 9
// 274.154 us; speedup vs baseline: 1.0777x; 1.0044x over previous
//
#include <hip/hip_runtime.h>

typedef short bf16x8 __attribute__((ext_vector_type(8)));
typedef float f32x4 __attribute__((ext_vector_type(4)));

#define ELLK 32
#define OCAP 4096
#define CSTRIDE 16  // ints between degree counters (64B apart): no same-line atomic aliasing

static __device__ __forceinline__ float4 f4zero() { return make_float4(0.f, 0.f, 0.f, 0.f); }

// round-to-nearest-even f32 -> bf16
static __device__ __forceinline__ unsigned short f2bf(float f) {
  unsigned u = __float_as_uint(f);
  u += 0x7FFFu + ((u >> 16) & 1u);
  return (unsigned short)(u >> 16);
}
// packed pair of bf16 (low = first elem) -> float2
static __device__ __forceinline__ float2 bf2x2(unsigned u) {
  float2 r;
  r.x = __uint_as_float(u << 16);
  r.y = __uint_as_float(u & 0xFFFF0000u);
  return r;
}

// ---------- setup: zero counters/ocount/pad-rows + weights -> bf16 in MFMA-FRAGMENT order ----------
// Wt[frag]: id = ((kk*8+nt)*64 + lane)*8 + j  ->  W[k = kk*32+quad*8+j][nn = nt*16+li]
__global__ void k_setup(const float* __restrict__ W1, const float* __restrict__ Wmu,
                        const float* __restrict__ Wlv, unsigned short* __restrict__ Wt1,
                        unsigned short* __restrict__ Wt2, uint4* __restrict__ cntz,
                        int* __restrict__ ocount, unsigned* __restrict__ A,
                        unsigned* __restrict__ H, int nz4, int nbz, int n) {
  int b = blockIdx.x;
  if (b < nbz) {
    int i = b * 256 + threadIdx.x;
    if (i < nz4) cntz[i] = make_uint4(0u, 0u, 0u, 0u);
    if (b == 0) {
      int t = threadIdx.x;
      if (t == 0) *ocount = 0;
      if (t < 64) A[(size_t)n * 64 + t] = 0u;               // zero pad row (A)
      else if (t < 128) H[(size_t)n * 64 + (t - 64)] = 0u;  // zero pad row (H)
    }
  } else {
    int id = (b - nbz) * 256 + threadIdx.x;  // 0..32767
    if (id < 16384) {
      int j = id & 7, lane = (id >> 3) & 63, g = id >> 9;  // g = kk*8+nt
      int kk = g >> 3, nt = g & 7, li = lane & 15, quad = lane >> 4;
      int nn = nt * 16 + li, k = kk * 32 + quad * 8 + j;
      Wt1[id] = f2bf(W1[k * 128 + nn]);
    } else {
      int id2 = id - 16384;
      int j = id2 & 7, lane = (id2 >> 3) & 63, g = id2 >> 9;
      int kk = g >> 3, nt = g & 7, li = lane & 15, quad = lane >> 4;
      int nn = nt * 16 + li, k = kk * 32 + quad * 8 + j;
      float v = (nn < 64) ? Wmu[k * 64 + nn] : Wlv[k * 64 + (nn - 64)];
      Wt2[id2] = f2bf(v);
    }
  }
}

// ---------- ELL fill (TRANSPOSED layout ell[pos][n]): 4 edges/thread ----------
// cached stores: plane working set ~1.6MB/XCD fits L2 -> write-combine (proven r8: -12us)
__global__ void k_fill(const int* __restrict__ ei, int* __restrict__ cnt,
                       int* __restrict__ ell, int2* __restrict__ ovf,
                       int* __restrict__ ocount, int E, int n) {
  int e0 = blockIdx.x * 1024 + threadIdx.x;
  int ss[4], dd[4], pos[4];
  bool ok[4];
#pragma unroll
  for (int k = 0; k < 4; ++k) {
    int e = e0 + k * 256;
    ok[k] = (e < E);
    ss[k] = ok[k] ? ei[e] : 0;
    dd[k] = ok[k] ? ei[E + e] : 0;
  }
#pragma unroll
  for (int k = 0; k < 4; ++k)
    pos[k] = ok[k] ? atomicAdd(&cnt[(size_t)dd[k] * CSTRIDE], 1) : ELLK;
#pragma unroll
  for (int k = 0; k < 4; ++k) {
    if (!ok[k]) continue;
    if (pos[k] < ELLK) {
      ell[(size_t)pos[k] * n + dd[k]] = ss[k];  // cached store -> L2 write-combine
    } else {
      int o = atomicAdd(ocount, 1);
      if (o < OCAP) ovf[o] = make_int2(dd[k], ss[k]);
    }
  }
}

// ---------- GEMM1 (MFMA, fragment-W): A = bf16(dis_i * (x @ W1)); emits dnorm/mflag ----------
__global__ __launch_bounds__(256, 6) void k_gemm1(
    const float* __restrict__ x, const unsigned short* __restrict__ Wt,
    const int* __restrict__ cnt, unsigned short* __restrict__ A,
    float* __restrict__ dnorm, unsigned* __restrict__ mflag, int n) {
  __shared__ unsigned short Xl[64 * 136];
  __shared__ float dnl[64];
  const int tid = threadIdx.x;
  const int row0 = blockIdx.x * 64;
  {
#pragma unroll
    for (int i = 0; i < 8; ++i) {
      int idx = tid + i * 256;  // 0..2047
      int r = idx >> 5, c = idx & 31;
      int gi = row0 + r;
      float4 v = (gi < n) ? ((const float4*)x)[(size_t)gi * 32 + c] : f4zero();
      ushort4 p;
      p.x = f2bf(v.x); p.y = f2bf(v.y); p.z = f2bf(v.z); p.w = f2bf(v.w);
      *(ushort4*)&Xl[r * 136 + c * 4] = p;
    }
  }
  if (tid < 64) {  // side product: dnorm/mflag (cnt is L2-hot after fill)
    int gi = row0 + tid;
    float dn = 0.f;
    if (gi < n) {
      int c = cnt[(size_t)gi * CSTRIDE];
      dn = rsqrtf((float)(c + 1));
      dnorm[gi] = dn;
      int mm = (c < ELLK) ? c : ELLK;
      mflag[gi] = (unsigned)mm | ((c > ELLK) ? 0x80000000u : 0u);
    }
    dnl[tid] = dn;
  }
  __syncthreads();

  const int wave = tid >> 6, lane = tid & 63;
  const int li = lane & 15, quad = lane >> 4;
  const int m0 = wave * 16;
  const bf16x8* Wf = (const bf16x8*)Wt;
  f32x4 acc[8];
#pragma unroll
  for (int t = 0; t < 8; ++t) acc[t] = (f32x4){0.f, 0.f, 0.f, 0.f};
#pragma unroll
  for (int kk = 0; kk < 4; ++kk) {
    int ko = kk * 32 + quad * 8;
    bf16x8 a = *(const bf16x8*)&Xl[(m0 + li) * 136 + ko];
    bf16x8 bf[8];
#pragma unroll
    for (int nt = 0; nt < 8; ++nt) bf[nt] = Wf[(kk * 8 + nt) * 64 + lane];
#pragma unroll
    for (int nt = 0; nt < 8; ++nt)
      acc[nt] = __builtin_amdgcn_mfma_f32_16x16x32_bf16(a, bf[nt], acc[nt], 0, 0, 0);
  }
  __syncthreads();  // MFMA reads of Xl done
  float dn[4];
#pragma unroll
  for (int r = 0; r < 4; ++r) dn[r] = dnl[m0 + quad * 4 + r];
#pragma unroll
  for (int nt = 0; nt < 8; ++nt)
#pragma unroll
    for (int r = 0; r < 4; ++r)
      Xl[(m0 + quad * 4 + r) * 136 + nt * 16 + li] = f2bf(acc[nt][r] * dn[r]);
  __syncthreads();
  {
    uint4* A4 = (uint4*)A;
#pragma unroll
    for (int i = 0; i < 4; ++i) {
      int idx = tid + i * 256;  // 0..1023
      int r = idx >> 4, c = idx & 15;
      int gi = row0 + r;
      if (gi < n) A4[(size_t)gi * 16 + c] = *(uint4*)&Xl[r * 136 + c * 8];
    }
  }
}

// ---------- SpMM layer 1: one wave/node, pure row-sum of pre-scaled A_bar ----------
__global__ __launch_bounds__(256, 8) void k_spmm1(
    const unsigned* __restrict__ mflag, const float* __restrict__ dnorm,
    const int* __restrict__ ell, const int2* __restrict__ ovf,
    const int* __restrict__ ocount, const unsigned* __restrict__ S,
    unsigned* __restrict__ D, const float2* __restrict__ bias, int n) {
  int wid = (blockIdx.x * blockDim.x + threadIdx.x) >> 6;
  if (wid >= n) return;
  int lane = threadIdx.x & 63;
  unsigned mf = mflag[wid];
  int m = (int)(mf & 0xFFFFu);
  float dsd = dnorm[wid];
  float2 acc = bf2x2(S[(size_t)wid * 64 + lane]);  // own row (pre-scaled self term)
  const int* ep = ell + wid;  // plane stride = n
  int nbt = (m + 7) >> 3;
  for (int b = 0; b < nbt; ++b) {
    int j0 = b * 8;
    int idx[8];
#pragma unroll
    for (int k = 0; k < 8; ++k) idx[k] = ep[(size_t)(j0 + k) * n];
#pragma unroll
    for (int k = 0; k < 8; ++k) idx[k] = (j0 + k < m) ? idx[k] : n;  // pads -> zero row
    unsigned u[8];
#pragma unroll
    for (int k = 0; k < 8; ++k) u[k] = S[(size_t)idx[k] * 64 + lane];
#pragma unroll
    for (int k = 0; k < 8; ++k) {
      float2 f = bf2x2(u[k]);
      acc.x += f.x;
      acc.y += f.y;
    }
  }
  if (mf & 0x80000000u) {  // overflow list scan (rare)
    int oc = *ocount;
    if (oc > OCAP) oc = OCAP;
    for (int k = 0; k < oc; ++k) {
      int2 e = ovf[k];
      if (e.x == wid) {
        float2 u0 = bf2x2(S[(size_t)e.y * 64 + lane]);
        acc.x += u0.x;
        acc.y += u0.y;
      }
    }
  }
  float2 b = bias[lane];
  float2 o;
  o.x = dsd * fmaxf(fmaf(dsd, acc.x, b.x), 0.f);
  o.y = dsd * fmaxf(fmaf(dsd, acc.y, b.y), 0.f);
  unsigned pk = (unsigned)f2bf(o.x) | ((unsigned)f2bf(o.y) << 16);
  D[(size_t)wid * 64 + lane] = pk;
}

// ---------- FUSED SpMM layer 2 + GEMM2: G stays in LDS ----------
// phase 1: each wave aggregates 16 nodes serially (r6 proven structure);
//          (256,8) doubles resident gather streams vs r6's (256,4) -> phase-1 rate up
// phase 2: MFMA with fragment-W: out = [G@Wmu+bmu | G@Wlv+blv]
__global__ __launch_bounds__(256, 8) void k_spmm2_gemm2(
    const unsigned* __restrict__ mflag, const float* __restrict__ dnorm,
    const int* __restrict__ ell, const int2* __restrict__ ovf,
    const int* __restrict__ ocount, const unsigned* __restrict__ H,
    const unsigned short* __restrict__ Wt, const float* __restrict__ bmu,
    const float* __restrict__ blv, float* __restrict__ out, int n) {
  __shared__ unsigned short Xl[64 * 136];
  const int tid = threadIdx.x;
  const int wave = tid >> 6, lane = tid & 63;
  const int row0 = blockIdx.x * 64;
#pragma unroll 1
  for (int i = 0; i < 16; ++i) {
    int nd = row0 + wave * 16 + i;
    unsigned pk = 0u;
    if (nd < n) {
      unsigned mf = mflag[nd];
      int m = (int)(mf & 0xFFFFu);
      float dsd = dnorm[nd];
      float2 acc = bf2x2(H[(size_t)nd * 64 + lane]);  // own row (pre-scaled)
      const int* ep = ell + nd;
      int nbt = (m + 7) >> 3;
      for (int b = 0; b < nbt; ++b) {
        int j0 = b * 8;
        int idx[8];
#pragma unroll
        for (int k = 0; k < 8; ++k) idx[k] = ep[(size_t)(j0 + k) * n];
#pragma unroll
        for (int k = 0; k < 8; ++k) idx[k] = (j0 + k < m) ? idx[k] : n;
        unsigned u[8];
#pragma unroll
        for (int k = 0; k < 8; ++k) u[k] = H[(size_t)idx[k] * 64 + lane];
#pragma unroll
        for (int k = 0; k < 8; ++k) {
          float2 f = bf2x2(u[k]);
          acc.x += f.x;
          acc.y += f.y;
        }
      }
      if (mf & 0x80000000u) {
        int oc = *ocount;
        if (oc > OCAP) oc = OCAP;
        for (int k = 0; k < oc; ++k) {
          int2 e = ovf[k];
          if (e.x == nd) {
            float2 u0 = bf2x2(H[(size_t)e.y * 64 + lane]);
            acc.x += u0.x;
            acc.y += u0.y;
          }
        }
      }
      float2 o;
      o.x = dsd * acc.x;
      o.y = dsd * acc.y;
      pk = (unsigned)f2bf(o.x) | ((unsigned)f2bf(o.y) << 16);
    }
    *(unsigned*)&Xl[(wave * 16 + i) * 136 + 2 * lane] = pk;  // G row -> LDS
  }
  __syncthreads();

  const int li = lane & 15, quad = lane >> 4;
  const int m0 = wave * 16;
  const bf16x8* Wf = (const bf16x8*)Wt;
  float bias[8];
#pragma unroll
  for (int nt = 0; nt < 8; ++nt) {
    int c = nt * 16 + li;
    bias[nt] = (c < 64) ? bmu[c] : blv[c - 64];
  }
  f32x4 acc[8];
#pragma unroll
  for (int t = 0; t < 8; ++t) acc[t] = (f32x4){0.f, 0.f, 0.f, 0.f};
#pragma unroll
  for (int kk = 0; kk < 4; ++kk) {
    int ko = kk * 32 + quad * 8;
    bf16x8 a = *(const bf16x8*)&Xl[(m0 + li) * 136 + ko];
    bf16x8 bf[8];
#pragma unroll
    for (int nt = 0; nt < 8; ++nt) bf[nt] = Wf[(kk * 8 + nt) * 64 + lane];
#pragma unroll
    for (int nt = 0; nt < 8; ++nt)
      acc[nt] = __builtin_amdgcn_mfma_f32_16x16x32_bf16(a, bf[nt], acc[nt], 0, 0, 0);
  }
#pragma unroll
  for (int nt = 0; nt < 8; ++nt) {
    int col = nt * 16 + li;
#pragma unroll
    for (int r = 0; r < 4; ++r) {
      int gi = row0 + m0 + quad * 4 + r;
      if (gi < n) {
        float v = acc[nt][r] + bias[nt];
        if (col < 64) out[(size_t)gi * 64 + col] = v;              // mu
        else          out[(size_t)(n + gi) * 64 + (col - 64)] = v; // logvar
      }
    }
  }
}

extern "C" void kernel_launch(void* const* d_in, const int* in_sizes, int n_in,
                              void* d_out, int out_size, void* d_ws, size_t ws_size,
                              hipStream_t stream) {
  const float* x   = (const float*)d_in[0];
  const int*   ei  = (const int*)d_in[1];   // [2, E], row0 = src, row1 = dst
  const float* W1  = (const float*)d_in[3];
  const float* b1  = (const float*)d_in[4];
  const float* Wmu = (const float*)d_in[5];
  const float* bmu = (const float*)d_in[6];
  const float* Wlv = (const float*)d_in[7];
  const float* blv = (const float*)d_in[8];
  float* out = (float*)d_out;

  const int n = in_sizes[0] / 128;
  const int E = in_sizes[1] / 2;

  // workspace layout (float units)
  float* ws = (float*)d_ws;
  size_t p = 0;
  int* cnt    = (int*)(ws + p); p += (size_t)n * CSTRIDE;  // spread counters (64B apart)
  int* ocount = (int*)(ws + p); p += 1;
  p = (p + 3) & ~(size_t)3;  // 16B align
  int* ell    = (int*)(ws + p); p += (size_t)n * ELLK;     // TRANSPOSED: [ELLK][n]
  int2* ovf   = (int2*)(ws + p); p += (size_t)OCAP * 2;
  unsigned* A = (unsigned*)(ws + p); p += (size_t)(n + 1) * 64;  // +1: zero pad row
  unsigned* H = (unsigned*)(ws + p); p += (size_t)(n + 1) * 64;
  unsigned short* Wt1 = (unsigned short*)(ws + p); p += 8192;  // 128x128 bf16 (fragment order)
  unsigned short* Wt2 = (unsigned short*)(ws + p); p += 8192;
  float* dnorm    = (float*)(ws + p); p += n;
  unsigned* mflag = (unsigned*)(ws + p); p += n;

  int nz4  = (n * CSTRIDE) / 4;
  int nbz  = (nz4 + 255) / 256;
  int eb   = (E + 1023) / 1024;
  int gblk = (n + 63) / 64;
  int sblk = (n + 3) / 4;

  // 1) zero counters/ocount/pad-rows + fragment-ordered weight transpose
  k_setup<<<nbz + 128, 256, 0, stream>>>(W1, Wmu, Wlv, Wt1, Wt2, (uint4*)cnt, ocount,
                                         A, H, nz4, nbz, n);
  // 2) ELL build (transposed planes, cached stores for L2 write-combine)
  k_fill<<<eb, 256, 0, stream>>>(ei, cnt, ell, ovf, ocount, E, n);
  // 3) A = bf16(dis_i * (x @ W1)) pre-scaled; emits dnorm/mflag as side product
  k_gemm1<<<gblk, 256, 0, stream>>>(x, Wt1, cnt, (unsigned short*)A, dnorm, mflag, n);
  // 4) layer 1: H_bar = dis*relu(dis*sum + b1)  (pre-scaled for layer 2)
  k_spmm1<<<sblk, 256, 0, stream>>>(mflag, dnorm, ell, ovf, ocount, A, H,
                                    (const float2*)b1, n);
  // 5) FUSED layer 2 + GEMM2 (single-stream phase-1, 8 blocks/CU): out = [mu | logvar]
  k_spmm2_gemm2<<<gblk, 256, 0, stream>>>(mflag, dnorm, ell, ovf, ocount, H, Wt2,
                                          bmu, blv, out, n);
}

// Round 10
// 271.599 us; speedup vs baseline: 1.0878x; 1.0094x over previous
//
#include <hip/hip_runtime.h>

typedef short bf16x8 __attribute__((ext_vector_type(8)));
typedef float f32x4 __attribute__((ext_vector_type(4)));

#define ELLK 32
#define OCAP 4096
#define CSTRIDE 16  // ints between degree counters (64B apart): no same-line atomic aliasing

static __device__ __forceinline__ float4 f4zero() { return make_float4(0.f, 0.f, 0.f, 0.f); }

// round-to-nearest-even f32 -> bf16
static __device__ __forceinline__ unsigned short f2bf(float f) {
  unsigned u = __float_as_uint(f);
  u += 0x7FFFu + ((u >> 16) & 1u);
  return (unsigned short)(u >> 16);
}
// packed pair of bf16 (low = first elem) -> float2
static __device__ __forceinline__ float2 bf2x2(unsigned u) {
  float2 r;
  r.x = __uint_as_float(u << 16);
  r.y = __uint_as_float(u & 0xFFFF0000u);
  return r;
}

// ---------- setup: zero counters/ocount/pad-rows + weights -> bf16 in MFMA-FRAGMENT order ----------
// Wt[frag]: id = ((kk*8+nt)*64 + lane)*8 + j  ->  W[k = kk*32+quad*8+j][nn = nt*16+li]
__global__ void k_setup(const float* __restrict__ W1, const float* __restrict__ Wmu,
                        const float* __restrict__ Wlv, unsigned short* __restrict__ Wt1,
                        unsigned short* __restrict__ Wt2, uint4* __restrict__ cntz,
                        int* __restrict__ ocount, unsigned* __restrict__ A,
                        unsigned* __restrict__ H, int nz4, int nbz, int n) {
  int b = blockIdx.x;
  if (b < nbz) {
    int i = b * 256 + threadIdx.x;
    if (i < nz4) cntz[i] = make_uint4(0u, 0u, 0u, 0u);
    if (b == 0) {
      int t = threadIdx.x;
      if (t == 0) *ocount = 0;
      if (t < 64) A[(size_t)n * 64 + t] = 0u;               // zero pad row (A)
      else if (t < 128) H[(size_t)n * 64 + (t - 64)] = 0u;  // zero pad row (H)
    }
  } else {
    int id = (b - nbz) * 256 + threadIdx.x;  // 0..32767
    if (id < 16384) {
      int j = id & 7, lane = (id >> 3) & 63, g = id >> 9;  // g = kk*8+nt
      int kk = g >> 3, nt = g & 7, li = lane & 15, quad = lane >> 4;
      int nn = nt * 16 + li, k = kk * 32 + quad * 8 + j;
      Wt1[id] = f2bf(W1[k * 128 + nn]);
    } else {
      int id2 = id - 16384;
      int j = id2 & 7, lane = (id2 >> 3) & 63, g = id2 >> 9;
      int kk = g >> 3, nt = g & 7, li = lane & 15, quad = lane >> 4;
      int nn = nt * 16 + li, k = kk * 32 + quad * 8 + j;
      float v = (nn < 64) ? Wmu[k * 64 + nn] : Wlv[k * 64 + (nn - 64)];
      Wt2[id2] = f2bf(v);
    }
  }
}

// ---------- ELL fill (TRANSPOSED layout ell[pos][n]): 4 edges/thread ----------
// cached stores: plane working set ~1.6MB/XCD fits L2 -> write-combine (proven r8)
__global__ void k_fill(const int* __restrict__ ei, int* __restrict__ cnt,
                       int* __restrict__ ell, int2* __restrict__ ovf,
                       int* __restrict__ ocount, int E, int n) {
  int e0 = blockIdx.x * 1024 + threadIdx.x;
  int ss[4], dd[4], pos[4];
  bool ok[4];
#pragma unroll
  for (int k = 0; k < 4; ++k) {
    int e = e0 + k * 256;
    ok[k] = (e < E);
    ss[k] = ok[k] ? ei[e] : 0;
    dd[k] = ok[k] ? ei[E + e] : 0;
  }
#pragma unroll
  for (int k = 0; k < 4; ++k)
    pos[k] = ok[k] ? atomicAdd(&cnt[(size_t)dd[k] * CSTRIDE], 1) : ELLK;
#pragma unroll
  for (int k = 0; k < 4; ++k) {
    if (!ok[k]) continue;
    if (pos[k] < ELLK) {
      ell[(size_t)pos[k] * n + dd[k]] = ss[k];  // cached store -> L2 write-combine
    } else {
      int o = atomicAdd(ocount, 1);
      if (o < OCAP) ovf[o] = make_int2(dd[k], ss[k]);
    }
  }
}

// ---------- GEMM1 (MFMA, fragment-W, DIRECT global A-fragments): A = bf16(dis_i*(x@W1)) ----------
// A-fragment global reads are line-coalesced: per (kk), wave reads 16 rows x 128 contiguous B
// (quad q covers bytes [q*32, q*32+32) of each row's 128B k-slice) -> no x LDS staging needed.
__global__ __launch_bounds__(256, 6) void k_gemm1(
    const float* __restrict__ x, const unsigned short* __restrict__ Wt,
    const int* __restrict__ cnt, unsigned short* __restrict__ A,
    float* __restrict__ dnorm, unsigned* __restrict__ mflag, int n) {
  __shared__ unsigned short Xl[64 * 136];  // output repack only
  __shared__ float dnl[64];
  const int tid = threadIdx.x;
  const int row0 = blockIdx.x * 64;
  if (tid < 64) {  // side product: dnorm/mflag (cnt is L2-hot after fill)
    int gi = row0 + tid;
    float dn = 0.f;
    if (gi < n) {
      int c = cnt[(size_t)gi * CSTRIDE];
      dn = rsqrtf((float)(c + 1));
      dnorm[gi] = dn;
      int mm = (c < ELLK) ? c : ELLK;
      mflag[gi] = (unsigned)mm | ((c > ELLK) ? 0x80000000u : 0u);
    }
    dnl[tid] = dn;
  }
  __syncthreads();  // dnl visible

  const int wave = tid >> 6, lane = tid & 63;
  const int li = lane & 15, quad = lane >> 4;
  const int m0 = wave * 16;
  const bf16x8* Wf = (const bf16x8*)Wt;

  const int arow = row0 + m0 + li;      // this lane's A-fragment row (fixed across kk)
  const bool rok = (arow < n);
  const float4* xr = (const float4*)x + (size_t)(rok ? arow : 0) * 32;

  f32x4 acc[8];
#pragma unroll
  for (int t = 0; t < 8; ++t) acc[t] = (f32x4){0.f, 0.f, 0.f, 0.f};
#pragma unroll
  for (int kk = 0; kk < 4; ++kk) {
    float4 v0 = rok ? xr[kk * 8 + quad * 2] : f4zero();
    float4 v1 = rok ? xr[kk * 8 + quad * 2 + 1] : f4zero();
    bf16x8 a = (bf16x8){(short)f2bf(v0.x), (short)f2bf(v0.y), (short)f2bf(v0.z),
                        (short)f2bf(v0.w), (short)f2bf(v1.x), (short)f2bf(v1.y),
                        (short)f2bf(v1.z), (short)f2bf(v1.w)};
    bf16x8 bf[8];
#pragma unroll
    for (int nt = 0; nt < 8; ++nt) bf[nt] = Wf[(kk * 8 + nt) * 64 + lane];
#pragma unroll
    for (int nt = 0; nt < 8; ++nt)
      acc[nt] = __builtin_amdgcn_mfma_f32_16x16x32_bf16(a, bf[nt], acc[nt], 0, 0, 0);
  }
  float dn[4];
#pragma unroll
  for (int r = 0; r < 4; ++r) dn[r] = dnl[m0 + quad * 4 + r];
#pragma unroll
  for (int nt = 0; nt < 8; ++nt)
#pragma unroll
    for (int r = 0; r < 4; ++r)
      Xl[(m0 + quad * 4 + r) * 136 + nt * 16 + li] = f2bf(acc[nt][r] * dn[r]);
  __syncthreads();
  {
    uint4* A4 = (uint4*)A;
#pragma unroll
    for (int i = 0; i < 4; ++i) {
      int idx = tid + i * 256;  // 0..1023
      int r = idx >> 4, c = idx & 15;
      int gi = row0 + r;
      if (gi < n) A4[(size_t)gi * 16 + c] = *(uint4*)&Xl[r * 136 + c * 8];
    }
  }
}

// ---------- SpMM layer 1: one wave/node, pure row-sum of pre-scaled A_bar ----------
__global__ __launch_bounds__(256, 8) void k_spmm1(
    const unsigned* __restrict__ mflag, const float* __restrict__ dnorm,
    const int* __restrict__ ell, const int2* __restrict__ ovf,
    const int* __restrict__ ocount, const unsigned* __restrict__ S,
    unsigned* __restrict__ D, const float2* __restrict__ bias, int n) {
  int wid = (blockIdx.x * blockDim.x + threadIdx.x) >> 6;
  if (wid >= n) return;
  int lane = threadIdx.x & 63;
  unsigned mf = mflag[wid];
  int m = (int)(mf & 0xFFFFu);
  float dsd = dnorm[wid];
  float2 acc = bf2x2(S[(size_t)wid * 64 + lane]);  // own row (pre-scaled self term)
  const int* ep = ell + wid;  // plane stride = n
  int nbt = (m + 7) >> 3;
  for (int b = 0; b < nbt; ++b) {
    int j0 = b * 8;
    int idx[8];
#pragma unroll
    for (int k = 0; k < 8; ++k) idx[k] = ep[(size_t)(j0 + k) * n];
#pragma unroll
    for (int k = 0; k < 8; ++k) idx[k] = (j0 + k < m) ? idx[k] : n;  // pads -> zero row
    unsigned u[8];
#pragma unroll
    for (int k = 0; k < 8; ++k) u[k] = S[(size_t)idx[k] * 64 + lane];
#pragma unroll
    for (int k = 0; k < 8; ++k) {
      float2 f = bf2x2(u[k]);
      acc.x += f.x;
      acc.y += f.y;
    }
  }
  if (mf & 0x80000000u) {  // overflow list scan (rare)
    int oc = *ocount;
    if (oc > OCAP) oc = OCAP;
    for (int k = 0; k < oc; ++k) {
      int2 e = ovf[k];
      if (e.x == wid) {
        float2 u0 = bf2x2(S[(size_t)e.y * 64 + lane]);
        acc.x += u0.x;
        acc.y += u0.y;
      }
    }
  }
  float2 b = bias[lane];
  float2 o;
  o.x = dsd * fmaxf(fmaf(dsd, acc.x, b.x), 0.f);
  o.y = dsd * fmaxf(fmaf(dsd, acc.y, b.y), 0.f);
  unsigned pk = (unsigned)f2bf(o.x) | ((unsigned)f2bf(o.y) << 16);
  D[(size_t)wid * 64 + lane] = pk;
}

// ---------- FUSED SpMM layer 2 + GEMM2: G stays in LDS ----------
// phase 1: 64-node LDS work queue shared by the block's 4 waves (load-balanced)
// phase 2: MFMA with fragment-W: out = [G@Wmu+bmu | G@Wlv+blv]
__global__ __launch_bounds__(256, 8) void k_spmm2_gemm2(
    const unsigned* __restrict__ mflag, const float* __restrict__ dnorm,
    const int* __restrict__ ell, const int2* __restrict__ ovf,
    const int* __restrict__ ocount, const unsigned* __restrict__ H,
    const unsigned short* __restrict__ Wt, const float* __restrict__ bmu,
    const float* __restrict__ blv, float* __restrict__ out, int n) {
  __shared__ unsigned short Xl[64 * 136];
  __shared__ int wq;
  const int tid = threadIdx.x;
  const int wave = tid >> 6, lane = tid & 63;
  const int row0 = blockIdx.x * 64;
  if (tid == 0) wq = 0;
  __syncthreads();

  for (;;) {
    int iloc = 0;
    if (lane == 0) iloc = atomicAdd(&wq, 1);
    iloc = __shfl(iloc, 0);
    if (iloc >= 64) break;
    int nd = row0 + iloc;
    unsigned pk = 0u;
    if (nd < n) {
      unsigned mf = mflag[nd];
      int m = (int)(mf & 0xFFFFu);
      float dsd = dnorm[nd];
      float2 acc = bf2x2(H[(size_t)nd * 64 + lane]);  // own row (pre-scaled)
      const int* ep = ell + nd;
      int nbt = (m + 7) >> 3;
      for (int b = 0; b < nbt; ++b) {
        int j0 = b * 8;
        int idx[8];
#pragma unroll
        for (int k = 0; k < 8; ++k) idx[k] = ep[(size_t)(j0 + k) * n];
#pragma unroll
        for (int k = 0; k < 8; ++k) idx[k] = (j0 + k < m) ? idx[k] : n;
        unsigned u[8];
#pragma unroll
        for (int k = 0; k < 8; ++k) u[k] = H[(size_t)idx[k] * 64 + lane];
#pragma unroll
        for (int k = 0; k < 8; ++k) {
          float2 f = bf2x2(u[k]);
          acc.x += f.x;
          acc.y += f.y;
        }
      }
      if (mf & 0x80000000u) {
        int oc = *ocount;
        if (oc > OCAP) oc = OCAP;
        for (int k = 0; k < oc; ++k) {
          int2 e = ovf[k];
          if (e.x == nd) {
            float2 u0 = bf2x2(H[(size_t)e.y * 64 + lane]);
            acc.x += u0.x;
            acc.y += u0.y;
          }
        }
      }
      float2 o;
      o.x = dsd * acc.x;
      o.y = dsd * acc.y;
      pk = (unsigned)f2bf(o.x) | ((unsigned)f2bf(o.y) << 16);
    }
    *(unsigned*)&Xl[iloc * 136 + 2 * lane] = pk;  // G row -> LDS
  }
  __syncthreads();

  const int li = lane & 15, quad = lane >> 4;
  const int m0 = wave * 16;
  const bf16x8* Wf = (const bf16x8*)Wt;
  float bias[8];
#pragma unroll
  for (int nt = 0; nt < 8; ++nt) {
    int c = nt * 16 + li;
    bias[nt] = (c < 64) ? bmu[c] : blv[c - 64];
  }
  f32x4 acc[8];
#pragma unroll
  for (int t = 0; t < 8; ++t) acc[t] = (f32x4){0.f, 0.f, 0.f, 0.f};
#pragma unroll
  for (int kk = 0; kk < 4; ++kk) {
    int ko = kk * 32 + quad * 8;
    bf16x8 a = *(const bf16x8*)&Xl[(m0 + li) * 136 + ko];
    bf16x8 bf[8];
#pragma unroll
    for (int nt = 0; nt < 8; ++nt) bf[nt] = Wf[(kk * 8 + nt) * 64 + lane];
#pragma unroll
    for (int nt = 0; nt < 8; ++nt)
      acc[nt] = __builtin_amdgcn_mfma_f32_16x16x32_bf16(a, bf[nt], acc[nt], 0, 0, 0);
  }
#pragma unroll
  for (int nt = 0; nt < 8; ++nt) {
    int col = nt * 16 + li;
#pragma unroll
    for (int r = 0; r < 4; ++r) {
      int gi = row0 + m0 + quad * 4 + r;
      if (gi < n) {
        float v = acc[nt][r] + bias[nt];
        if (col < 64) out[(size_t)gi * 64 + col] = v;              // mu
        else          out[(size_t)(n + gi) * 64 + (col - 64)] = v; // logvar
      }
    }
  }
}

extern "C" void kernel_launch(void* const* d_in, const int* in_sizes, int n_in,
                              void* d_out, int out_size, void* d_ws, size_t ws_size,
                              hipStream_t stream) {
  const float* x   = (const float*)d_in[0];
  const int*   ei  = (const int*)d_in[1];   // [2, E], row0 = src, row1 = dst
  const float* W1  = (const float*)d_in[3];
  const float* b1  = (const float*)d_in[4];
  const float* Wmu = (const float*)d_in[5];
  const float* bmu = (const float*)d_in[6];
  const float* Wlv = (const float*)d_in[7];
  const float* blv = (const float*)d_in[8];
  float* out = (float*)d_out;

  const int n = in_sizes[0] / 128;
  const int E = in_sizes[1] / 2;

  // workspace layout (float units)
  float* ws = (float*)d_ws;
  size_t p = 0;
  int* cnt    = (int*)(ws + p); p += (size_t)n * CSTRIDE;  // spread counters (64B apart)
  int* ocount = (int*)(ws + p); p += 1;
  p = (p + 3) & ~(size_t)3;  // 16B align
  int* ell    = (int*)(ws + p); p += (size_t)n * ELLK;     // TRANSPOSED: [ELLK][n]
  int2* ovf   = (int2*)(ws + p); p += (size_t)OCAP * 2;
  unsigned* A = (unsigned*)(ws + p); p += (size_t)(n + 1) * 64;  // +1: zero pad row
  unsigned* H = (unsigned*)(ws + p); p += (size_t)(n + 1) * 64;
  unsigned short* Wt1 = (unsigned short*)(ws + p); p += 8192;  // 128x128 bf16 (fragment order)
  unsigned short* Wt2 = (unsigned short*)(ws + p); p += 8192;
  float* dnorm    = (float*)(ws + p); p += n;
  unsigned* mflag = (unsigned*)(ws + p); p += n;

  int nz4  = (n * CSTRIDE) / 4;
  int nbz  = (nz4 + 255) / 256;
  int eb   = (E + 1023) / 1024;
  int gblk = (n + 63) / 64;
  int sblk = (n + 3) / 4;

  // 1) zero counters/ocount/pad-rows + fragment-ordered weight transpose
  k_setup<<<nbz + 128, 256, 0, stream>>>(W1, Wmu, Wlv, Wt1, Wt2, (uint4*)cnt, ocount,
                                         A, H, nz4, nbz, n);
  // 2) ELL build (transposed planes, cached stores for L2 write-combine)
  k_fill<<<eb, 256, 0, stream>>>(ei, cnt, ell, ovf, ocount, E, n);
  // 3) A = bf16(dis_i * (x @ W1)) pre-scaled; direct global A-fragments (no x staging)
  k_gemm1<<<gblk, 256, 0, stream>>>(x, Wt1, cnt, (unsigned short*)A, dnorm, mflag, n);
  // 4) layer 1: H_bar = dis*relu(dis*sum + b1)  (pre-scaled for layer 2)
  k_spmm1<<<sblk, 256, 0, stream>>>(mflag, dnorm, ell, ovf, ocount, A, H,
                                    (const float2*)b1, n);
  // 5) FUSED layer 2 + GEMM2 (work-queue phase-1): out = [mu | logvar]
  k_spmm2_gemm2<<<gblk, 256, 0, stream>>>(mflag, dnorm, ell, ovf, ocount, H, Wt2,
                                          bmu, blv, out, n);
}